// Round 10
// baseline (636.745 us; speedup 1.0000x reference)
//
#include <hip/hip_runtime.h>
#include <hip/hip_bf16.h>
#include <math.h>

typedef __bf16 bf16;
typedef __attribute__((ext_vector_type(4))) __bf16 bf16x4;
typedef __attribute__((ext_vector_type(8))) __bf16 bf16x8;
typedef __attribute__((ext_vector_type(4))) float f32x4;

#define N_NODES 20000
#define N_EDGES 320000
#define E2 (N_EDGES + N_NODES)   // 340000 edges incl self-loops
#define F_IN 50
#define D1 1024                  // H1*C1
#define NP12 2048                // padded GEMM out-cols, layer 2 ([W|Wl])
#define NP3 896                  // padded GEMM out-cols, layer 3 (726+121=847 -> 896)
#define SG 2048                  // row stride of GEMM output buffer
#define KA 320                   // layer-1 fused K: 4*64 aggx + 64 x

// params pool element offsets (bf16 pool)
#define PO_A1S 0
#define PO_A1D 1024
#define PO_B1  2048
#define PO_BL1 3072
#define PO_A2S 4096
#define PO_A2D 5120
#define PO_B2  6144
#define PO_BL2 7168
#define PO_A3S 8192
#define PO_A3D 8918
#define PO_B3  9644
#define PO_BL3 9765
#define PO_END 9886

// k_prep block-range sizes
#define PB_PADX  5000            // N_NODES*64/256
#define PB_WF1   1280            // D1*KA/256
#define PB_PAR   39              // ceil(PO_END/256)
#define PB_LOG1  5000            // N_NODES/4
#define PB_WC2   512             // wcatT layer 2: 16 x 32
#define PB_WC3   224             // wcatT layer 3: 16 x 14

__device__ __forceinline__ int clampi(int v, int lo, int hi)
{
    return v < lo ? lo : (v > hi ? hi : v);
}

__device__ __forceinline__ float loadf(const void* p, long idx, int isb)
{
    return isb ? (float)((const bf16*)p)[idx] : ((const float*)p)[idx];
}

__device__ __forceinline__ int loadei(const int* ei, long idx, int i64)
{
    return i64 ? ei[2 * idx] : ei[idx];
}

// --------------------------------------------------------------- detect -----
__global__ void k_detect(const int* __restrict__ ei,
                         const unsigned short* __restrict__ xw,
                         int* __restrict__ flags)
{
    if (blockIdx.x != 0 || threadIdx.x != 0) return;
    int allz = 1;
    for (int i = 0; i < 128; ++i)
        if (ei[2 * i + 1] != 0) { allz = 0; break; }
    int inr = 0;
    for (int i = 0; i < 128; ++i) {
        int e = (xw[2 * i] >> 7) & 0xFF;
        if (e >= 100 && e <= 140) inr++;
    }
    flags[0] = allz;
    flags[1] = (inr >= 64) ? 1 : 0;
}

// ---------------------------------------------------------------- GEMM ------
// m97-style 128x128 tile, BK=64. BACT: fused bias+ELU epilogue.
// LOGH=4 (layer 2): fused attention-logit epilogue — for GAT cols (<1024),
// each 64-col wave-span lies in ONE head (256|span base); per row-fragment
// compute 4-col partial of acc . a2s/a2d, 16-lane frow shfl-reduce, then
// one f32 atomicAdd per (row, head). es/ed must be pre-zeroed.
template <bool BACT, int LOGH>
__global__ __launch_bounds__(256) void k_gemm(const bf16* __restrict__ A,
                                              const bf16* __restrict__ Bt,
                                              bf16* __restrict__ C,
                                              int M, int K, int lda, int ldb, int ldc,
                                              int mtiles, int ntiles,
                                              const bf16* __restrict__ bias,
                                              const bf16* __restrict__ aps,
                                              const bf16* __restrict__ apd,
                                              float* __restrict__ es,
                                              float* __restrict__ ed)
{
    __shared__ bf16 As[128 * 64];
    __shared__ bf16 Bs[128 * 64];

    int id = blockIdx.x;
    int gfull = mtiles >> 3;
    int base  = gfull * 8 * ntiles;
    int x, y;
    if (id < base) {
        int gsz = 8 * ntiles;
        int g = id / gsz;
        int r = id - g * gsz;
        x = g * 8 + (r & 7);
        y = r >> 3;
    } else {
        int rem = mtiles - (gfull << 3);
        int r = id - base;
        x = (gfull << 3) + r % rem;
        y = r / rem;
    }
    const int m0 = x * 128;
    const int n0 = y * 128;

    const int tid  = threadIdx.x;
    const int wave = tid >> 6;
    const int lane = tid & 63;
    const int wm   = (wave >> 1) * 64;
    const int wn   = (wave & 1) * 64;
    const int frow  = lane & 15;

    const int srow = wave * 32 + (lane >> 3);
    const int scol = (((lane & 7) ^ (lane >> 3)) * 8);

    f32x4 acc[4][4];
#pragma unroll
    for (int i = 0; i < 4; ++i)
#pragma unroll
        for (int j = 0; j < 4; ++j)
#pragma unroll
            for (int r = 0; r < 4; ++r) acc[i][j][r] = 0.f;

    for (int k0 = 0; k0 < K; k0 += 64) {
#pragma unroll
        for (int i = 0; i < 4; ++i) {
            int ra = srow + i * 8;
            int ga = m0 + ra; if (ga > M - 1) ga = M - 1;   // junk rows -> discarded C rows
            __builtin_amdgcn_global_load_lds(
                (const __attribute__((address_space(1))) void*)(A + (size_t)ga * lda + k0 + scol),
                (__attribute__((address_space(3))) void*)(As + wave * 2048 + i * 512),
                16, 0, 0);
            int gb = n0 + ra;
            __builtin_amdgcn_global_load_lds(
                (const __attribute__((address_space(1))) void*)(Bt + (size_t)gb * ldb + k0 + scol),
                (__attribute__((address_space(3))) void*)(Bs + wave * 2048 + i * 512),
                16, 0, 0);
        }
        __syncthreads();
#pragma unroll
        for (int kk = 0; kk < 2; ++kk) {
            const int coff = (((kk * 4 + (lane >> 4)) ^ (frow & 7)) << 3);
            bf16x8 af[4], bfr[4];
#pragma unroll
            for (int i = 0; i < 4; ++i) {
                af[i]  = *(const bf16x8*)(As + (wm + i * 16 + frow) * 64 + coff);
                bfr[i] = *(const bf16x8*)(Bs + (wn + i * 16 + frow) * 64 + coff);
            }
#pragma unroll
            for (int i = 0; i < 4; ++i)
#pragma unroll
                for (int j = 0; j < 4; ++j)
                    acc[i][j] = __builtin_amdgcn_mfma_f32_16x16x32_bf16(af[i], bfr[j], acc[i][j], 0, 0, 0);
        }
        __syncthreads();
    }

    if constexpr (LOGH == 4) {
        if (n0 + wn < 1024) {                    // GAT half only
            const int h = (n0 + wn) >> 8;        // head of this 64-col span
            float asv[4], adv[4];
#pragma unroll
            for (int j = 0; j < 4; ++j) {
                int col = n0 + wn + j * 16 + frow;
                asv[j] = (float)aps[col];
                adv[j] = (float)apd[col];
            }
#pragma unroll
            for (int i = 0; i < 4; ++i) {
#pragma unroll
                for (int r = 0; r < 4; ++r) {
                    float ps = 0.f, pd = 0.f;
#pragma unroll
                    for (int j = 0; j < 4; ++j) {
                        ps += acc[i][j][r] * asv[j];
                        pd += acc[i][j][r] * adv[j];
                    }
#pragma unroll
                    for (int off = 8; off; off >>= 1) {
                        ps += __shfl_xor(ps, off);
                        pd += __shfl_xor(pd, off);
                    }
                    int row = m0 + wm + i * 16 + (lane >> 4) * 4 + r;
                    if (frow == 0 && row < M) {
                        atomicAdd(&es[row * 4 + h], ps);
                        atomicAdd(&ed[row * 4 + h], pd);
                    }
                }
            }
        }
    }

#pragma unroll
    for (int i = 0; i < 4; ++i) {
#pragma unroll
        for (int j = 0; j < 4; ++j) {
            int rbase = m0 + wm + i * 16 + (lane >> 4) * 4;
            int col   = n0 + wn + j * 16 + frow;
            if constexpr (BACT) {
                float bv = (float)bias[col];
#pragma unroll
                for (int r = 0; r < 4; ++r) {
                    int row = rbase + r;
                    if (row < M) {
                        float v = acc[i][j][r] + bv;
                        v = (v > 0.f) ? v : (__expf(v) - 1.f);
                        C[(size_t)row * ldc + col] = (bf16)v;
                    }
                }
            } else {
#pragma unroll
                for (int r = 0; r < 4; ++r) {
                    int row = rbase + r;
                    if (row < M) C[(size_t)row * ldc + col] = (bf16)acc[i][j][r];
                }
            }
        }
    }
}

// ------------------------------------------------------------ prep kernels --
// ws[k][h] = sum_c W1[k, h*256+c]*a1s[h,c]; wd likewise; bsum = b1+bl1.
__global__ __launch_bounds__(256) void k_veca(const void* __restrict__ W1,
                                              const void* __restrict__ a1s,
                                              const void* __restrict__ a1d,
                                              const void* __restrict__ b1,
                                              const void* __restrict__ bl1,
                                              float* __restrict__ ws, float* __restrict__ wd,
                                              bf16* __restrict__ bsum,
                                              const int* __restrict__ flags)
{
    const int isb = flags[1];
    const int k = blockIdx.x;          // 0..63
    const int h = threadIdx.x >> 6;
    const int c0 = threadIdx.x & 63;
    float s = 0.f, d = 0.f;
    if (k < F_IN) {
        for (int c = c0; c < 256; c += 64) {
            float wv = loadf(W1, (long)k * D1 + h * 256 + c, isb);
            s += wv * loadf(a1s, h * 256 + c, isb);
            d += wv * loadf(a1d, h * 256 + c, isb);
        }
    }
#pragma unroll
    for (int off = 32; off; off >>= 1) {
        s += __shfl_xor(s, off);
        d += __shfl_xor(d, off);
    }
    if (c0 == 0) { ws[k * 4 + h] = s; wd[k * 4 + h] = d; }
    if (k < 4) {
        int j = k * 256 + threadIdx.x;
        bsum[j] = (bf16)(loadf(b1, j, isb) + loadf(bl1, j, isb));
    }
}

struct P12 { const void* s[12]; };

// merged prep: padx | wfuse1 | params | logits1-from-x | wcatT-L2 | wcatT-L3.
// wcatT ranges fold the weight transposes in (weights-only deps, R9).
__global__ __launch_bounds__(256) void k_prep(const void* __restrict__ x,
                                              const void* __restrict__ W1,
                                              const void* __restrict__ Wl1,
                                              const void* __restrict__ W2,
                                              const void* __restrict__ Wl2,
                                              const void* __restrict__ W3,
                                              const void* __restrict__ Wl3,
                                              P12 ps,
                                              bf16* __restrict__ A2,
                                              bf16* __restrict__ Bt,
                                              bf16* __restrict__ Bt2,
                                              bf16* __restrict__ Bt3,
                                              bf16* __restrict__ pool,
                                              const float* __restrict__ ws,
                                              const float* __restrict__ wd,
                                              float* __restrict__ es,
                                              float* __restrict__ ed,
                                              const int* __restrict__ flags)
{
    __shared__ bf16 T[64][65];
    const int isb = flags[1];
    int b = blockIdx.x;

    if (b < PB_PADX) {                       // ---- x -> A2[n*KA + 256 + k]
        int idx = b * 256 + threadIdx.x;
        int n = idx >> 6, k = idx & 63;
        A2[(size_t)n * KA + 256 + k] = (k < F_IN) ? (bf16)loadf(x, (long)n * F_IN + k, isb)
                                                  : (bf16)0.f;
        return;
    }
    b -= PB_PADX;

    if (b < PB_WF1) {                        // ---- fused layer-1 B^T
        int idx = b * 256 + threadIdx.x;
        int j = idx / KA;
        int kp = idx - j * KA;
        float v = 0.f;
        if (kp < 256) {
            int hp = kp >> 6, k = kp & 63;
            if ((j >> 8) == hp && k < F_IN) v = loadf(W1, (long)k * D1 + j, isb);
        } else {
            int k = kp - 256;
            if (k < F_IN) v = loadf(Wl1, (long)k * D1 + j, isb);
        }
        Bt[idx] = (bf16)v;
        return;
    }
    b -= PB_WF1;

    if (b < PB_PAR) {                        // ---- params pool
        const int off[13] = {PO_A1S, PO_A1D, PO_B1, PO_BL1, PO_A2S, PO_A2D, PO_B2,
                             PO_BL2, PO_A3S, PO_A3D, PO_B3, PO_BL3, PO_END};
        int idx = b * 256 + threadIdx.x;
        if (idx < PO_END) {
            int seg = 0;
            while (idx >= off[seg + 1]) seg++;
            pool[idx] = (bf16)loadf(ps.s[seg], idx - off[seg], isb);
        }
        return;
    }
    b -= PB_PAR;

    if (b < PB_LOG1) {                       // ---- layer-1 logits from x
        const int wave = threadIdx.x >> 6;
        const int lane = threadIdx.x & 63;
        const int n = b * 4 + wave;
        if (n >= N_NODES) return;
        float xv = (lane < F_IN) ? loadf(x, (long)n * F_IN + lane, isb) : 0.f;
        f32x4 wsv = *(const f32x4*)(ws + lane * 4);
        f32x4 wdv = *(const f32x4*)(wd + lane * 4);
        float s[4], d[4];
#pragma unroll
        for (int h = 0; h < 4; ++h) { s[h] = xv * wsv[h]; d[h] = xv * wdv[h]; }
#pragma unroll
        for (int off = 32; off; off >>= 1)
#pragma unroll
            for (int h = 0; h < 4; ++h) {
                s[h] += __shfl_xor(s[h], off);
                d[h] += __shfl_xor(d[h], off);
            }
        if (lane == 0) {
#pragma unroll
            for (int h = 0; h < 4; ++h) { es[n * 4 + h] = s[h]; ed[n * 4 + h] = d[h]; }
        }
        return;
    }
    b -= PB_LOG1;

    // ---- wcatT ranges: Bt*[n][k] = [Wa | Wb | 0](k, n)
    const bf16* dummy;
    const void* Wa; const void* Wb; bf16* Bo; int split, da, db, bx, by;
    if (b < PB_WC2) {
        Wa = W2; Wb = Wl2; Bo = Bt2; split = 1024; da = 1024; db = 1024;
        bx = b & 15; by = b >> 4;
    } else {
        b -= PB_WC2;
        Wa = W3; Wb = Wl3; Bo = Bt3; split = 726; da = 726; db = 121;
        bx = b % 16; by = b / 16;
    }
    {
        const int k0 = bx * 64;
        const int n0 = by * 64;
        const int r = threadIdx.x >> 6;
        const int c = threadIdx.x & 63;
        const int n = n0 + c;
#pragma unroll
        for (int kk = 0; kk < 16; ++kk) {
            int k = k0 + r + kk * 4;
            float v = 0.f;
            if (n < split)           v = loadf(Wa, (long)k * da + n, isb);
            else if (n < split + db) v = loadf(Wb, (long)k * db + (n - split), isb);
            T[r + kk * 4][c] = (bf16)v;
        }
        __syncthreads();
#pragma unroll
        for (int kk = 0; kk < 16; ++kk) {
            int nn = r + kk * 4;
            Bo[(size_t)(n0 + nn) * 1024 + k0 + c] = T[c][nn];
        }
    }
}

// ------------------------------------------------------------- CSR build ----
__global__ void k_count(const int* __restrict__ ei, int* __restrict__ cnt,
                        const int* __restrict__ flags)
{
    int e = blockIdx.x * 256 + threadIdx.x;
    if (e >= E2) return;
    int i64 = flags[0];
    int d = (e < N_EDGES) ? loadei(ei, (long)N_EDGES + e, i64) : (e - N_EDGES);
    d = clampi(d, 0, N_NODES - 1);
    atomicAdd(&cnt[d], 1);
}

__global__ __launch_bounds__(256) void k_scan(const int* __restrict__ cnt,
                                              int* __restrict__ rp,
                                              int* __restrict__ cur)
{
    __shared__ int ssum[256];
    int tid = threadIdx.x;
    const int chunk = (N_NODES + 255) / 256;
    int lo = tid * chunk;
    int hi = lo + chunk; if (hi > N_NODES) hi = N_NODES;
    int s = 0;
    for (int i = lo; i < hi; ++i) s += cnt[i];
    ssum[tid] = s;
    __syncthreads();
    if (tid == 0) {
        int run = 0;
        for (int i = 0; i < 256; ++i) { int t = ssum[i]; ssum[i] = run; run += t; }
        rp[N_NODES] = run;
    }
    __syncthreads();
    int run = ssum[tid];
    for (int i = lo; i < hi; ++i) { rp[i] = run; cur[i] = run; run += cnt[i]; }
}

__global__ void k_fill(const int* __restrict__ ei, int* __restrict__ cur,
                       int* __restrict__ ss, const int* __restrict__ flags)
{
    int e = blockIdx.x * 256 + threadIdx.x;
    if (e >= E2) return;
    int i64 = flags[0];
    int s, d;
    if (e < N_EDGES) {
        s = loadei(ei, e, i64);
        d = loadei(ei, (long)N_EDGES + e, i64);
    } else {
        s = e - N_EDGES; d = s;
    }
    s = clampi(s, 0, N_NODES - 1);
    d = clampi(d, 0, N_NODES - 1);
    int pos = atomicAdd(&cur[d], 1);
    if (pos >= 0 && pos < E2) ss[pos] = s;
}

// ----------------------------------------------------- attention kernels ----
// R8: wave-per-node layer-1 aggregate. 4 nodes/block, ZERO barriers.
__global__ __launch_bounds__(256) void k_aggxw(bf16* __restrict__ A2,
                                               const float* __restrict__ es,
                                               const float* __restrict__ ed,
                                               const int* __restrict__ rp,
                                               const int* __restrict__ ss)
{
    __shared__ float sal[4][4][65];
    __shared__ int   ssrc[4][64];

    const int w    = threadIdx.x >> 6;
    const int lane = threadIdx.x & 63;
    const int n    = blockIdx.x * 4 + w;
    if (n >= N_NODES) return;

    int r0 = clampi(rp[n], 0, E2);
    int r1 = clampi(rp[n + 1], r0, E2);
    const int deg = r1 - r0;

    f32x4 edn = *(const f32x4*)(ed + n * 4);

    // pass A: online softmax stats (max + denom), all 64 lanes over edges
    float mx[4] = {-1e30f, -1e30f, -1e30f, -1e30f};
    float sm[4] = {0.f, 0.f, 0.f, 0.f};
    for (int c0 = 0; c0 < deg; c0 += 64) {
        const int e = c0 + lane;
        const bool val = (e < deg);
        const int s = val ? clampi(ss[r0 + e], 0, N_NODES - 1) : 0;
        f32x4 esv = *(const f32x4*)(es + s * 4);
        float w4[4], mc[4];
#pragma unroll
        for (int h = 0; h < 4; ++h) {
            float v = esv[h] + edn[h];
            v = (v > 0.f) ? v : 0.2f * v;
            w4[h] = val ? v : -1e30f;
            mc[h] = w4[h];
        }
#pragma unroll
        for (int off = 32; off; off >>= 1)
#pragma unroll
            for (int h = 0; h < 4; ++h) mc[h] = fmaxf(mc[h], __shfl_xor(mc[h], off));
        float ps[4];
#pragma unroll
        for (int h = 0; h < 4; ++h) {
            float mn = fmaxf(mx[h], mc[h]);
            float f  = __expf(mx[h] - mn);
            ps[h] = __expf(w4[h] - mn);
            mx[h] = mn;
            sm[h] *= f;
        }
#pragma unroll
        for (int off = 32; off; off >>= 1)
#pragma unroll
            for (int h = 0; h < 4; ++h) ps[h] += __shfl_xor(ps[h], off);
#pragma unroll
        for (int h = 0; h < 4; ++h) sm[h] += ps[h];
    }
    float sinv[4];
#pragma unroll
    for (int h = 0; h < 4; ++h) sinv[h] = 1.f / fmaxf(sm[h], 1e-16f);

    // pass B: alpha fill + 8-edge-per-instruction gather
    const int g  = lane >> 3;          // edge slot 0..7
    const int cb = (lane & 7) * 8;     // channel block 0..56
    float acc[4][8];
#pragma unroll
    for (int h = 0; h < 4; ++h)
#pragma unroll
        for (int j = 0; j < 8; ++j) acc[h][j] = 0.f;

    for (int c0 = 0; c0 < deg; c0 += 64) {
        const int ce = min(64, deg - c0);
        const bool val = (lane < ce);
        const int e = c0 + lane;
        const int s = val ? clampi(ss[r0 + e], 0, N_NODES - 1) : 0;
        f32x4 esv = *(const f32x4*)(es + s * 4);
#pragma unroll
        for (int h = 0; h < 4; ++h) {
            float v = esv[h] + edn[h];
            v = (v > 0.f) ? v : 0.2f * v;
            sal[w][h][lane] = val ? __expf(v - mx[h]) * sinv[h] : 0.f;
        }
        ssrc[w][lane] = s;
        // wave-synchronous LDS RAW: same-wave ds ops execute in order.
        const int ce8 = (ce + 7) & ~7;
        for (int eb = 0; eb < ce8; eb += 8) {
            const int sg = ssrc[w][eb + g];
            bf16x8 xv = *(const bf16x8*)(A2 + (size_t)sg * KA + 256 + cb);
            float a[4];
#pragma unroll
            for (int h = 0; h < 4; ++h) a[h] = sal[w][h][eb + g];
#pragma unroll
            for (int h = 0; h < 4; ++h)
#pragma unroll
                for (int j = 0; j < 8; ++j) acc[h][j] += a[h] * (float)xv[j];
        }
    }

    // fold across the 8 edge-groups
#pragma unroll
    for (int off = 8; off <= 32; off <<= 1)
#pragma unroll
        for (int h = 0; h < 4; ++h)
#pragma unroll
            for (int j = 0; j < 8; ++j) acc[h][j] += __shfl_xor(acc[h][j], off);

    if (g < 4) {                       // lane group g writes head g
        bf16x8 ov;
#pragma unroll
        for (int j = 0; j < 8; ++j) {
            float v = (g == 0) ? acc[0][j]
                    : (g == 1) ? acc[1][j]
                    : (g == 2) ? acc[2][j] : acc[3][j];
            ov[j] = (bf16)v;
        }
        *(bf16x8*)(A2 + (size_t)n * KA + g * 64 + cb) = ov;
    }
}

// R9: vectorized layer-3 logits (wave per node, 12 ch/lane, LDS atomic fold).
__global__ __launch_bounds__(256) void k_logits3w(const bf16* __restrict__ G,
                                                  const bf16* __restrict__ as_,
                                                  const bf16* __restrict__ ad_,
                                                  float* __restrict__ es,
                                                  float* __restrict__ ed)
{
    __shared__ float sE[4][8], sD[4][8];
    const int w    = threadIdx.x >> 6;
    const int lane = threadIdx.x & 63;
    const int n    = blockIdx.x * 4 + w;
    if (n >= N_NODES) return;

    if (lane < 8) { sE[w][lane] = 0.f; sD[w][lane] = 0.f; }

    const int c0 = lane * 12;          // lanes 0..60 cover 0..731 (726 valid)
    int hA = min(c0 / 121, 5), hB = min((c0 + 11) / 121, 5);
    float sA = 0.f, sB = 0.f, dA = 0.f, dB = 0.f;
    if (c0 < 726) {
        const bf16* gp = G + (size_t)n * SG + c0;
        bf16x4 g0 = *(const bf16x4*)gp;
        bf16x4 g1 = *(const bf16x4*)(gp + 4);
        bf16x4 g2 = *(const bf16x4*)(gp + 8);
        bf16x4 s0 = *(const bf16x4*)(as_ + c0);
        bf16x4 s1 = *(const bf16x4*)(as_ + c0 + 4);
        bf16x4 s2 = *(const bf16x4*)(as_ + c0 + 8);
        bf16x4 d0 = *(const bf16x4*)(ad_ + c0);
        bf16x4 d1 = *(const bf16x4*)(ad_ + c0 + 4);
        bf16x4 d2 = *(const bf16x4*)(ad_ + c0 + 8);
#pragma unroll
        for (int j = 0; j < 12; ++j) {
            int c = c0 + j;
            if (c < 726) {
                float gv = (float)((j < 4) ? g0[j] : (j < 8) ? g1[j - 4] : g2[j - 8]);
                float sv = (float)((j < 4) ? s0[j] : (j < 8) ? s1[j - 4] : s2[j - 8]);
                float dv = (float)((j < 4) ? d0[j] : (j < 8) ? d1[j - 4] : d2[j - 8]);
                if (c / 121 == hA) { sA += gv * sv; dA += gv * dv; }
                else               { sB += gv * sv; dB += gv * dv; }
            }
        }
    }
    // wave-synchronous LDS atomic fold (no barrier: single wave, in-order)
    atomicAdd(&sE[w][hA], sA);
    atomicAdd(&sD[w][hA], dA);
    if (hB != hA) {
        atomicAdd(&sE[w][hB], sB);
        atomicAdd(&sD[w][hB], dB);
    }
    if (lane < 6) {
        es[n * 6 + lane] = sE[w][lane];
        ed[n * 6 + lane] = sD[w][lane];
    }
}

// R7: wave-per-node aggregate for layer 2 (H=4, C=256, D=1024).
__global__ __launch_bounds__(256) void k_aggw(const bf16* __restrict__ G,
                                              const bf16* __restrict__ S,
                                              const float* __restrict__ es,
                                              const float* __restrict__ ed,
                                              const int* __restrict__ rp,
                                              const int* __restrict__ ss,
                                              const bf16* __restrict__ bgat,
                                              const bf16* __restrict__ bskip,
                                              bf16* __restrict__ out, int sout)
{
    __shared__ float sal[4][4][65];    // [wave][head][edge] (+pad)
    __shared__ int   ssrc[4][64];

    const int w    = threadIdx.x >> 6;
    const int lane = threadIdx.x & 63;
    const int n    = blockIdx.x * 4 + w;
    if (n >= N_NODES) return;

    int r0 = clampi(rp[n], 0, E2);
    int r1 = clampi(rp[n + 1], r0, E2);
    const int deg = r1 - r0;

    f32x4 edn = *(const f32x4*)(ed + n * 4);

    // ---- pass A: online max+sum (replicated across lanes via all-reduce)
    float mx[4] = {-1e30f, -1e30f, -1e30f, -1e30f};
    float sm[4] = {0.f, 0.f, 0.f, 0.f};
    for (int c0 = 0; c0 < deg; c0 += 64) {
        const int e = c0 + lane;
        const bool val = (e < deg);
        const int s = val ? clampi(ss[r0 + e], 0, N_NODES - 1) : 0;
        f32x4 esv = *(const f32x4*)(es + s * 4);
        float w4[4], mc[4];
#pragma unroll
        for (int h = 0; h < 4; ++h) {
            float v = esv[h] + edn[h];
            v = (v > 0.f) ? v : 0.2f * v;
            w4[h] = val ? v : -1e30f;
            mc[h] = w4[h];
        }
#pragma unroll
        for (int off = 32; off; off >>= 1)
#pragma unroll
            for (int h = 0; h < 4; ++h) mc[h] = fmaxf(mc[h], __shfl_xor(mc[h], off));
        float ps[4];
#pragma unroll
        for (int h = 0; h < 4; ++h) {
            float mn = fmaxf(mx[h], mc[h]);
            float f  = __expf(mx[h] - mn);
            ps[h] = __expf(w4[h] - mn);
            mx[h] = mn;
            sm[h] *= f;
        }
#pragma unroll
        for (int off = 32; off; off >>= 1)
#pragma unroll
            for (int h = 0; h < 4; ++h) ps[h] += __shfl_xor(ps[h], off);
#pragma unroll
        for (int h = 0; h < 4; ++h) sm[h] += ps[h];
    }
    float sinv[4];
#pragma unroll
    for (int h = 0; h < 4; ++h) sinv[h] = 1.f / fmaxf(sm[h], 1e-16f);

    // ---- pass B: per-chunk alpha fill + gather
    const int myh  = lane >> 4;
    const int c0ch = lane * 16;
    float acc[16];
#pragma unroll
    for (int j = 0; j < 16; ++j) acc[j] = 0.f;

    for (int c0 = 0; c0 < deg; c0 += 64) {
        const int ce = min(64, deg - c0);
        const bool val = (lane < ce);
        const int e = c0 + lane;
        const int s = val ? clampi(ss[r0 + e], 0, N_NODES - 1) : 0;
        f32x4 esv = *(const f32x4*)(es + s * 4);
#pragma unroll
        for (int h = 0; h < 4; ++h) {
            float v = esv[h] + edn[h];
            v = (v > 0.f) ? v : 0.2f * v;
            sal[w][h][lane] = val ? __expf(v - mx[h]) * sinv[h] : 0.f;
        }
        ssrc[w][lane] = s;
        const int ce4 = (ce + 3) & ~3;
        for (int eb = 0; eb < ce4; eb += 4) {
            int sg[4]; float a[4];
#pragma unroll
            for (int p = 0; p < 4; ++p) {
                sg[p] = ssrc[w][eb + p];
                a[p]  = sal[w][myh][eb + p];
            }
            bf16x8 g0[4], g1[4];
#pragma unroll
            for (int p = 0; p < 4; ++p) {
                const bf16* gp = G + (size_t)sg[p] * SG + c0ch;
                g0[p] = *(const bf16x8*)gp;
                g1[p] = *(const bf16x8*)(gp + 8);
            }
#pragma unroll
            for (int p = 0; p < 4; ++p) {
#pragma unroll
                for (int j = 0; j < 8; ++j) acc[j]     += a[p] * (float)g0[p][j];
#pragma unroll
                for (int j = 0; j < 8; ++j) acc[j + 8] += a[p] * (float)g1[p][j];
            }
        }
    }

    // ---- epilogue: + bgat + skip + bskip, ELU, store 32B
    bf16x8 bg0 = *(const bf16x8*)(bgat + c0ch);
    bf16x8 bg1 = *(const bf16x8*)(bgat + c0ch + 8);
    bf16x8 sk0 = *(const bf16x8*)(S + (size_t)n * SG + c0ch);
    bf16x8 sk1 = *(const bf16x8*)(S + (size_t)n * SG + c0ch + 8);
    bf16x8 bs0 = *(const bf16x8*)(bskip + c0ch);
    bf16x8 bs1 = *(const bf16x8*)(bskip + c0ch + 8);
    bf16x8 ov0, ov1;
#pragma unroll
    for (int j = 0; j < 8; ++j) {
        float v = acc[j] + (float)bg0[j] + (float)sk0[j] + (float)bs0[j];
        v = (v > 0.f) ? v : (__expf(v) - 1.f);
        ov0[j] = (bf16)v;
        float u = acc[j + 8] + (float)bg1[j] + (float)sk1[j] + (float)bs1[j];
        u = (u > 0.f) ? u : (__expf(u) - 1.f);
        ov1[j] = (bf16)u;
    }
    *(bf16x8*)(out + (size_t)n * sout + c0ch)     = ov0;
    *(bf16x8*)(out + (size_t)n * sout + c0ch + 8) = ov1;
}

// R8: wave-per-node aggregate for layer 3 (H=6, C=121, MEAN over heads).
__global__ __launch_bounds__(256) void k_aggw3(const bf16* __restrict__ G,
                                               const bf16* __restrict__ S,
                                               const float* __restrict__ es,
                                               const float* __restrict__ ed,
                                               const int* __restrict__ rp,
                                               const int* __restrict__ ss,
                                               const bf16* __restrict__ bgat,
                                               const bf16* __restrict__ bskip,
                                               void* __restrict__ out, int sout,
                                               const int* __restrict__ flags)
{
    __shared__ float sal[4][6][65];
    __shared__ int   ssrc[4][64];
    __shared__ float sfold[4][728];

    const int w    = threadIdx.x >> 6;
    const int lane = threadIdx.x & 63;
    const int n    = blockIdx.x * 4 + w;
    if (n >= N_NODES) return;

    int r0 = clampi(rp[n], 0, E2);
    int r1 = clampi(rp[n + 1], r0, E2);
    const int deg = r1 - r0;

    float edn[6];
#pragma unroll
    for (int h = 0; h < 6; ++h) edn[h] = ed[n * 6 + h];

    // pass A: online softmax stats, 6 heads
    float mx[6], sm[6];
#pragma unroll
    for (int h = 0; h < 6; ++h) { mx[h] = -1e30f; sm[h] = 0.f; }
    for (int c0 = 0; c0 < deg; c0 += 64) {
        const int e = c0 + lane;
        const bool val = (e < deg);
        const int s = val ? clampi(ss[r0 + e], 0, N_NODES - 1) : 0;
        const float* ep = es + (size_t)s * 6;
        float w6[6], mc[6];
#pragma unroll
        for (int h = 0; h < 6; ++h) {
            float v = ep[h] + edn[h];
            v = (v > 0.f) ? v : 0.2f * v;
            w6[h] = val ? v : -1e30f;
            mc[h] = w6[h];
        }
#pragma unroll
        for (int off = 32; off; off >>= 1)
#pragma unroll
            for (int h = 0; h < 6; ++h) mc[h] = fmaxf(mc[h], __shfl_xor(mc[h], off));
        float ps[6];
#pragma unroll
        for (int h = 0; h < 6; ++h) {
            float mn = fmaxf(mx[h], mc[h]);
            float f  = __expf(mx[h] - mn);
            ps[h] = __expf(w6[h] - mn);
            mx[h] = mn;
            sm[h] *= f;
        }
#pragma unroll
        for (int off = 32; off; off >>= 1)
#pragma unroll
            for (int h = 0; h < 6; ++h) ps[h] += __shfl_xor(ps[h], off);
#pragma unroll
        for (int h = 0; h < 6; ++h) sm[h] += ps[h];
    }
    float sinv[6];
#pragma unroll
    for (int h = 0; h < 6; ++h) sinv[h] = 1.f / fmaxf(sm[h], 1e-16f);

    // pass B: lane owns 12 channels at c0ch; junk channels >=726 are
    // accumulated (in-bounds, finite: skip/pad region) but never written.
    const int c0ch = lane * 12;
    const int hA = min(c0ch / 121, 5);
    const int hB = min((c0ch + 11) / 121, 5);
    bool jA[12];
#pragma unroll
    for (int j = 0; j < 12; ++j) jA[j] = (min((c0ch + j) / 121, 5) == hA);

    float acc[12];
#pragma unroll
    for (int j = 0; j < 12; ++j) acc[j] = 0.f;

    for (int c0 = 0; c0 < deg; c0 += 64) {
        const int ce = min(64, deg - c0);
        const bool val = (lane < ce);
        const int e = c0 + lane;
        const int s = val ? clampi(ss[r0 + e], 0, N_NODES - 1) : 0;
        const float* ep = es + (size_t)s * 6;
#pragma unroll
        for (int h = 0; h < 6; ++h) {
            float v = ep[h] + edn[h];
            v = (v > 0.f) ? v : 0.2f * v;
            sal[w][h][lane] = val ? __expf(v - mx[h]) * sinv[h] : 0.f;
        }
        ssrc[w][lane] = s;
        const int ce4 = (ce + 3) & ~3;
        for (int eb = 0; eb < ce4; eb += 4) {
            int sg[4]; float aL[4], aH[4];
#pragma unroll
            for (int p = 0; p < 4; ++p) {
                sg[p] = ssrc[w][eb + p];
                aL[p] = sal[w][hA][eb + p];
                aH[p] = sal[w][hB][eb + p];
            }
#pragma unroll
            for (int p = 0; p < 4; ++p) {
                const bf16* gp = G + (size_t)sg[p] * SG + c0ch;
                bf16x4 g0 = *(const bf16x4*)gp;
                bf16x4 g1 = *(const bf16x4*)(gp + 4);
                bf16x4 g2 = *(const bf16x4*)(gp + 8);
#pragma unroll
                for (int j = 0; j < 4; ++j) acc[j]     += (jA[j]     ? aL[p] : aH[p]) * (float)g0[j];
#pragma unroll
                for (int j = 0; j < 4; ++j) acc[4 + j] += (jA[4 + j] ? aL[p] : aH[p]) * (float)g1[j];
#pragma unroll
                for (int j = 0; j < 4; ++j) acc[8 + j] += (jA[8 + j] ? aL[p] : aH[p]) * (float)g2[j];
            }
        }
    }

    // head-mean epilogue via wave-local LDS fold (wave-synchronous, in-order)
#pragma unroll
    for (int j = 0; j < 12; ++j) {
        int c = c0ch + j;
        if (c < 726) sfold[w][c] = acc[j];
    }
    const int outbf = flags[1];
    for (int c = lane; c < 121; c += 64) {
        float v = 0.f;
#pragma unroll
        for (int h = 0; h < 6; ++h) v += sfold[w][h * 121 + c];
        v *= (1.f / 6.f);
        v += (float)bgat[c] + (float)S[(size_t)n * SG + c] + (float)bskip[c];
        if (outbf) ((bf16*)out)[(size_t)n * sout + c] = (bf16)v;
        else       ((float*)out)[(size_t)n * sout + c] = v;
    }
}

// ----------------------------------------------------------------- launch ---
extern "C" void kernel_launch(void* const* d_in, const int* in_sizes, int n_in,
                              void* d_out, int out_size, void* d_ws, size_t ws_size,
                              hipStream_t stream)
{
    const void* x   = d_in[0];
    const int*  ei  = (const int*)d_in[1];
    const void* W1  = d_in[2];
    const void* Wl1 = d_in[6];
    const void* W2  = d_in[8];
    const void* Wl2 = d_in[12];
    const void* W3  = d_in[14];
    const void* Wl3 = d_in[18];

    P12 ps;
    ps.s[0] = d_in[3];  ps.s[1] = d_in[4];  ps.s[2] = d_in[5];  ps.s[3] = d_in[7];
    ps.s[4] = d_in[9];  ps.s[5] = d_in[10]; ps.s[6] = d_in[11]; ps.s[7] = d_in[13];
    ps.s[8] = d_in[15]; ps.s[9] = d_in[16]; ps.s[10] = d_in[17]; ps.s[11] = d_in[19];

    char* w = (char*)d_ws;
    auto alloc = [&](size_t bytes) {
        char* p = w;
        w += (bytes + 255) & ~(size_t)255;
        return p;
    };
    int*   flags = (int*)alloc(64);
    int*   cnt   = (int*)alloc((size_t)N_NODES * 4);
    int*   rp    = (int*)alloc((size_t)(N_NODES + 1) * 4);
    int*   cur   = (int*)alloc((size_t)N_NODES * 4);
    int*   ss    = (int*)alloc((size_t)E2 * 4);
    float* es    = (float*)alloc((size_t)N_NODES * 6 * 4);   // 480000B, 256-aligned
    float* ed    = (float*)alloc((size_t)N_NODES * 6 * 4);   // contiguous with es
    bf16*  pool  = (bf16*)alloc((size_t)PO_END * 2);
    float* ws1   = (float*)alloc((size_t)64 * 4 * 4);
    float* wd1   = (float*)alloc((size_t)64 * 4 * 4);
    bf16*  bsum  = (bf16*)alloc((size_t)D1 * 2);
    bf16*  Bt    = (bf16*)alloc((size_t)D1 * KA * 2);        // layer-1 fused B^T
    bf16*  Bt2   = (bf16*)alloc((size_t)NP12 * 1024 * 2);    // layer-2 B^T
    bf16*  Bt3   = (bf16*)alloc((size_t)NP3 * 1024 * 2);     // layer-3 B^T
    bf16*  X     = (bf16*)alloc((size_t)N_NODES * D1 * 2);   // x1/x2
    bf16*  WS    = (bf16*)alloc((size_t)N_NODES * SG * 2);   // GEMM out [gat|skip]
    bf16*  A2    = WS;   // layer-1 A'' [N x KA] aliases WS (dead during layer 1)

    k_detect<<<1, 64, 0, stream>>>(ei, (const unsigned short*)x, flags);

    hipMemsetAsync(cnt, 0, N_NODES * 4, stream);
    k_count<<<(E2 + 255) / 256, 256, 0, stream>>>(ei, cnt, flags);
    k_scan<<<1, 256, 0, stream>>>(cnt, rp, cur);
    k_fill<<<(E2 + 255) / 256, 256, 0, stream>>>(ei, cur, ss, flags);

    const dim3 blk(256);
    const int MT = (N_NODES + 127) / 128;   // 157

    // ---- layer 1: veca -> merged prep (incl wcatT L2/L3) -> aggxw -> GEMM
    k_veca<<<64, 256, 0, stream>>>(W1, ps.s[0], ps.s[1], ps.s[2], ps.s[3],
                                   ws1, wd1, bsum, flags);
    k_prep<<<PB_PADX + PB_WF1 + PB_PAR + PB_LOG1 + PB_WC2 + PB_WC3, 256, 0, stream>>>(
        x, W1, Wl1, W2, Wl2, W3, Wl3, ps, A2, Bt, Bt2, Bt3, pool, ws1, wd1, es, ed, flags);
    k_aggxw<<<N_NODES / 4, 256, 0, stream>>>(A2, es, ed, rp, ss);
    k_gemm<true, 0><<<MT * (D1 / 128), blk, 0, stream>>>(
        A2, Bt, X, N_NODES, KA, KA, KA, D1, MT, D1 / 128, bsum,
        nullptr, nullptr, nullptr, nullptr);   // x1 = ELU(...)

    // ---- layer 2: GEMM with fused logits (es/ed zeroed first), then aggw
    hipMemsetAsync(es, 0, (size_t)N_NODES * 6 * 4 * 2, stream);   // es+ed contiguous
    k_gemm<false, 4><<<MT * (NP12 / 128), blk, 0, stream>>>(
        X, Bt2, WS, N_NODES, 1024, 1024, 1024, SG, MT, NP12 / 128, nullptr,
        pool + PO_A2S, pool + PO_A2D, es, ed);
    k_aggw<<<N_NODES / 4, 256, 0, stream>>>(
        WS, WS + D1, es, ed, rp, ss, pool + PO_B2, pool + PO_BL2, X, D1);

    // ---- layer 3: GEMM, vectorized logits, aggregate
    k_gemm<false, 0><<<MT * (NP3 / 128), blk, 0, stream>>>(
        X, Bt3, WS, N_NODES, 1024, 1024, 1024, SG, MT, NP3 / 128, nullptr,
        nullptr, nullptr, nullptr, nullptr);
    k_logits3w<<<N_NODES / 4, 256, 0, stream>>>(WS, pool + PO_A3S, pool + PO_A3D, es, ed);
    k_aggw3<<<N_NODES / 4, 256, 0, stream>>>(
        WS, WS + 726, es, ed, rp, ss, pool + PO_B3, pool + PO_BL3, d_out, 121, flags);
}

// Round 11
// 631.200 us; speedup vs baseline: 1.0088x; 1.0088x over previous
//
#include <hip/hip_runtime.h>
#include <hip/hip_bf16.h>
#include <math.h>

typedef __bf16 bf16;
typedef __attribute__((ext_vector_type(4))) __bf16 bf16x4;
typedef __attribute__((ext_vector_type(8))) __bf16 bf16x8;
typedef __attribute__((ext_vector_type(4))) float f32x4;

#define N_NODES 20000
#define N_EDGES 320000
#define E2 (N_EDGES + N_NODES)   // 340000 edges incl self-loops
#define F_IN 50
#define D1 1024                  // H1*C1
#define NP12 2048                // padded GEMM out-cols, layer 2 ([W|Wl])
#define NP3 896                  // padded GEMM out-cols, layer 3 (726+121=847 -> 896)
#define SG 2048                  // row stride of GEMM output buffer
#define KA 320                   // layer-1 fused K: 4*64 aggx + 64 x

// params pool element offsets (bf16 pool)
#define PO_A1S 0
#define PO_A1D 1024
#define PO_B1  2048
#define PO_BL1 3072
#define PO_A2S 4096
#define PO_A2D 5120
#define PO_B2  6144
#define PO_BL2 7168
#define PO_A3S 8192
#define PO_A3D 8918
#define PO_B3  9644
#define PO_BL3 9765
#define PO_END 9886

// k_prep block-range sizes
#define PB_PADX  5000            // N_NODES*64/256
#define PB_WF1   1280            // D1*KA/256
#define PB_PAR   39              // ceil(PO_END/256)
#define PB_LOG1  5000            // N_NODES/4
#define PB_WC2   512             // wcatT layer 2: 16 x 32
#define PB_WC3   224             // wcatT layer 3: 16 x 14

__device__ __forceinline__ int clampi(int v, int lo, int hi)
{
    return v < lo ? lo : (v > hi ? hi : v);
}

__device__ __forceinline__ float loadf(const void* p, long idx, int isb)
{
    return isb ? (float)((const bf16*)p)[idx] : ((const float*)p)[idx];
}

__device__ __forceinline__ int loadei(const int* ei, long idx, int i64)
{
    return i64 ? ei[2 * idx] : ei[idx];
}

// --------------------------------------------------------------- detect -----
__global__ void k_detect(const int* __restrict__ ei,
                         const unsigned short* __restrict__ xw,
                         int* __restrict__ flags)
{
    if (blockIdx.x != 0 || threadIdx.x != 0) return;
    int allz = 1;
    for (int i = 0; i < 128; ++i)
        if (ei[2 * i + 1] != 0) { allz = 0; break; }
    int inr = 0;
    for (int i = 0; i < 128; ++i) {
        int e = (xw[2 * i] >> 7) & 0xFF;
        if (e >= 100 && e <= 140) inr++;
    }
    flags[0] = allz;
    flags[1] = (inr >= 64) ? 1 : 0;
}

// ---------------------------------------------------------------- GEMM ------
// m97-style 128x128 tile, BK=64. BACT: fused bias+ELU epilogue.
// (R10: reverted the fused-logits epilogue — it cost +23 us on the hot
// dispatch vs the ~20 us kernel it deleted. 256^2 8-phase also dead.)
template <bool BACT>
__global__ __launch_bounds__(256) void k_gemm(const bf16* __restrict__ A,
                                              const bf16* __restrict__ Bt,
                                              bf16* __restrict__ C,
                                              int M, int K, int lda, int ldb, int ldc,
                                              int mtiles, int ntiles,
                                              const bf16* __restrict__ bias)
{
    __shared__ bf16 As[128 * 64];
    __shared__ bf16 Bs[128 * 64];

    int id = blockIdx.x;
    int gfull = mtiles >> 3;
    int base  = gfull * 8 * ntiles;
    int x, y;
    if (id < base) {
        int gsz = 8 * ntiles;
        int g = id / gsz;
        int r = id - g * gsz;
        x = g * 8 + (r & 7);
        y = r >> 3;
    } else {
        int rem = mtiles - (gfull << 3);
        int r = id - base;
        x = (gfull << 3) + r % rem;
        y = r / rem;
    }
    const int m0 = x * 128;
    const int n0 = y * 128;

    const int tid  = threadIdx.x;
    const int wave = tid >> 6;
    const int lane = tid & 63;
    const int wm   = (wave >> 1) * 64;
    const int wn   = (wave & 1) * 64;
    const int frow  = lane & 15;

    const int srow = wave * 32 + (lane >> 3);
    const int scol = (((lane & 7) ^ (lane >> 3)) * 8);

    f32x4 acc[4][4];
#pragma unroll
    for (int i = 0; i < 4; ++i)
#pragma unroll
        for (int j = 0; j < 4; ++j)
#pragma unroll
            for (int r = 0; r < 4; ++r) acc[i][j][r] = 0.f;

    for (int k0 = 0; k0 < K; k0 += 64) {
#pragma unroll
        for (int i = 0; i < 4; ++i) {
            int ra = srow + i * 8;
            int ga = m0 + ra; if (ga > M - 1) ga = M - 1;   // junk rows -> discarded C rows
            __builtin_amdgcn_global_load_lds(
                (const __attribute__((address_space(1))) void*)(A + (size_t)ga * lda + k0 + scol),
                (__attribute__((address_space(3))) void*)(As + wave * 2048 + i * 512),
                16, 0, 0);
            int gb = n0 + ra;
            __builtin_amdgcn_global_load_lds(
                (const __attribute__((address_space(1))) void*)(Bt + (size_t)gb * ldb + k0 + scol),
                (__attribute__((address_space(3))) void*)(Bs + wave * 2048 + i * 512),
                16, 0, 0);
        }
        __syncthreads();
#pragma unroll
        for (int kk = 0; kk < 2; ++kk) {
            const int coff = (((kk * 4 + (lane >> 4)) ^ (frow & 7)) << 3);
            bf16x8 af[4], bfr[4];
#pragma unroll
            for (int i = 0; i < 4; ++i) {
                af[i]  = *(const bf16x8*)(As + (wm + i * 16 + frow) * 64 + coff);
                bfr[i] = *(const bf16x8*)(Bs + (wn + i * 16 + frow) * 64 + coff);
            }
#pragma unroll
            for (int i = 0; i < 4; ++i)
#pragma unroll
                for (int j = 0; j < 4; ++j)
                    acc[i][j] = __builtin_amdgcn_mfma_f32_16x16x32_bf16(af[i], bfr[j], acc[i][j], 0, 0, 0);
        }
        __syncthreads();
    }

#pragma unroll
    for (int i = 0; i < 4; ++i) {
#pragma unroll
        for (int j = 0; j < 4; ++j) {
            int rbase = m0 + wm + i * 16 + (lane >> 4) * 4;
            int col   = n0 + wn + j * 16 + frow;
            if constexpr (BACT) {
                float bv = (float)bias[col];
#pragma unroll
                for (int r = 0; r < 4; ++r) {
                    int row = rbase + r;
                    if (row < M) {
                        float v = acc[i][j][r] + bv;
                        v = (v > 0.f) ? v : (__expf(v) - 1.f);
                        C[(size_t)row * ldc + col] = (bf16)v;
                    }
                }
            } else {
#pragma unroll
                for (int r = 0; r < 4; ++r) {
                    int row = rbase + r;
                    if (row < M) C[(size_t)row * ldc + col] = (bf16)acc[i][j][r];
                }
            }
        }
    }
}

// ------------------------------------------------------------ prep kernels --
// ws[k][h] = sum_c W1[k, h*256+c]*a1s[h,c]; wd likewise; bsum = b1+bl1.
__global__ __launch_bounds__(256) void k_veca(const void* __restrict__ W1,
                                              const void* __restrict__ a1s,
                                              const void* __restrict__ a1d,
                                              const void* __restrict__ b1,
                                              const void* __restrict__ bl1,
                                              float* __restrict__ ws, float* __restrict__ wd,
                                              bf16* __restrict__ bsum,
                                              const int* __restrict__ flags)
{
    const int isb = flags[1];
    const int k = blockIdx.x;          // 0..63
    const int h = threadIdx.x >> 6;
    const int c0 = threadIdx.x & 63;
    float s = 0.f, d = 0.f;
    if (k < F_IN) {
        for (int c = c0; c < 256; c += 64) {
            float wv = loadf(W1, (long)k * D1 + h * 256 + c, isb);
            s += wv * loadf(a1s, h * 256 + c, isb);
            d += wv * loadf(a1d, h * 256 + c, isb);
        }
    }
#pragma unroll
    for (int off = 32; off; off >>= 1) {
        s += __shfl_xor(s, off);
        d += __shfl_xor(d, off);
    }
    if (c0 == 0) { ws[k * 4 + h] = s; wd[k * 4 + h] = d; }
    if (k < 4) {
        int j = k * 256 + threadIdx.x;
        bsum[j] = (bf16)(loadf(b1, j, isb) + loadf(bl1, j, isb));
    }
}

struct P12 { const void* s[12]; };

// merged prep: padx | wfuse1 | params | logits1-from-x | wcatT-L2 | wcatT-L3.
__global__ __launch_bounds__(256) void k_prep(const void* __restrict__ x,
                                              const void* __restrict__ W1,
                                              const void* __restrict__ Wl1,
                                              const void* __restrict__ W2,
                                              const void* __restrict__ Wl2,
                                              const void* __restrict__ W3,
                                              const void* __restrict__ Wl3,
                                              P12 ps,
                                              bf16* __restrict__ A2,
                                              bf16* __restrict__ Bt,
                                              bf16* __restrict__ Bt2,
                                              bf16* __restrict__ Bt3,
                                              bf16* __restrict__ pool,
                                              const float* __restrict__ ws,
                                              const float* __restrict__ wd,
                                              float* __restrict__ es,
                                              float* __restrict__ ed,
                                              const int* __restrict__ flags)
{
    __shared__ bf16 T[64][65];
    const int isb = flags[1];
    int b = blockIdx.x;

    if (b < PB_PADX) {                       // ---- x -> A2[n*KA + 256 + k]
        int idx = b * 256 + threadIdx.x;
        int n = idx >> 6, k = idx & 63;
        A2[(size_t)n * KA + 256 + k] = (k < F_IN) ? (bf16)loadf(x, (long)n * F_IN + k, isb)
                                                  : (bf16)0.f;
        return;
    }
    b -= PB_PADX;

    if (b < PB_WF1) {                        // ---- fused layer-1 B^T
        int idx = b * 256 + threadIdx.x;
        int j = idx / KA;
        int kp = idx - j * KA;
        float v = 0.f;
        if (kp < 256) {
            int hp = kp >> 6, k = kp & 63;
            if ((j >> 8) == hp && k < F_IN) v = loadf(W1, (long)k * D1 + j, isb);
        } else {
            int k = kp - 256;
            if (k < F_IN) v = loadf(Wl1, (long)k * D1 + j, isb);
        }
        Bt[idx] = (bf16)v;
        return;
    }
    b -= PB_WF1;

    if (b < PB_PAR) {                        // ---- params pool
        const int off[13] = {PO_A1S, PO_A1D, PO_B1, PO_BL1, PO_A2S, PO_A2D, PO_B2,
                             PO_BL2, PO_A3S, PO_A3D, PO_B3, PO_BL3, PO_END};
        int idx = b * 256 + threadIdx.x;
        if (idx < PO_END) {
            int seg = 0;
            while (idx >= off[seg + 1]) seg++;
            pool[idx] = (bf16)loadf(ps.s[seg], idx - off[seg], isb);
        }
        return;
    }
    b -= PB_PAR;

    if (b < PB_LOG1) {                       // ---- layer-1 logits from x
        const int wave = threadIdx.x >> 6;
        const int lane = threadIdx.x & 63;
        const int n = b * 4 + wave;
        if (n >= N_NODES) return;
        float xv = (lane < F_IN) ? loadf(x, (long)n * F_IN + lane, isb) : 0.f;
        f32x4 wsv = *(const f32x4*)(ws + lane * 4);
        f32x4 wdv = *(const f32x4*)(wd + lane * 4);
        float s[4], d[4];
#pragma unroll
        for (int h = 0; h < 4; ++h) { s[h] = xv * wsv[h]; d[h] = xv * wdv[h]; }
#pragma unroll
        for (int off = 32; off; off >>= 1)
#pragma unroll
            for (int h = 0; h < 4; ++h) {
                s[h] += __shfl_xor(s[h], off);
                d[h] += __shfl_xor(d[h], off);
            }
        if (lane == 0) {
#pragma unroll
            for (int h = 0; h < 4; ++h) { es[n * 4 + h] = s[h]; ed[n * 4 + h] = d[h]; }
        }
        return;
    }
    b -= PB_LOG1;

    // ---- wcatT ranges: Bt*[n][k] = [Wa | Wb | 0](k, n)
    const void* Wa; const void* Wb; bf16* Bo; int split, da, db, bx, by;
    if (b < PB_WC2) {
        Wa = W2; Wb = Wl2; Bo = Bt2; split = 1024; da = 1024; db = 1024;
        bx = b & 15; by = b >> 4;
    } else {
        b -= PB_WC2;
        Wa = W3; Wb = Wl3; Bo = Bt3; split = 726; da = 726; db = 121;
        bx = b % 16; by = b / 16;
    }
    {
        const int k0 = bx * 64;
        const int n0 = by * 64;
        const int r = threadIdx.x >> 6;
        const int c = threadIdx.x & 63;
        const int n = n0 + c;
#pragma unroll
        for (int kk = 0; kk < 16; ++kk) {
            int k = k0 + r + kk * 4;
            float v = 0.f;
            if (n < split)           v = loadf(Wa, (long)k * da + n, isb);
            else if (n < split + db) v = loadf(Wb, (long)k * db + (n - split), isb);
            T[r + kk * 4][c] = (bf16)v;
        }
        __syncthreads();
#pragma unroll
        for (int kk = 0; kk < 16; ++kk) {
            int nn = r + kk * 4;
            Bo[(size_t)(n0 + nn) * 1024 + k0 + c] = T[c][nn];
        }
    }
}

// ------------------------------------------------------------- CSR build ----
__global__ void k_count(const int* __restrict__ ei, int* __restrict__ cnt,
                        const int* __restrict__ flags)
{
    int e = blockIdx.x * 256 + threadIdx.x;
    if (e >= E2) return;
    int i64 = flags[0];
    int d = (e < N_EDGES) ? loadei(ei, (long)N_EDGES + e, i64) : (e - N_EDGES);
    d = clampi(d, 0, N_NODES - 1);
    atomicAdd(&cnt[d], 1);
}

__global__ __launch_bounds__(256) void k_scan(const int* __restrict__ cnt,
                                              int* __restrict__ rp,
                                              int* __restrict__ cur)
{
    __shared__ int ssum[256];
    int tid = threadIdx.x;
    const int chunk = (N_NODES + 255) / 256;
    int lo = tid * chunk;
    int hi = lo + chunk; if (hi > N_NODES) hi = N_NODES;
    int s = 0;
    for (int i = lo; i < hi; ++i) s += cnt[i];
    ssum[tid] = s;
    __syncthreads();
    if (tid == 0) {
        int run = 0;
        for (int i = 0; i < 256; ++i) { int t = ssum[i]; ssum[i] = run; run += t; }
        rp[N_NODES] = run;
    }
    __syncthreads();
    int run = ssum[tid];
    for (int i = lo; i < hi; ++i) { rp[i] = run; cur[i] = run; run += cnt[i]; }
}

__global__ void k_fill(const int* __restrict__ ei, int* __restrict__ cur,
                       int* __restrict__ ss, const int* __restrict__ flags)
{
    int e = blockIdx.x * 256 + threadIdx.x;
    if (e >= E2) return;
    int i64 = flags[0];
    int s, d;
    if (e < N_EDGES) {
        s = loadei(ei, e, i64);
        d = loadei(ei, (long)N_EDGES + e, i64);
    } else {
        s = e - N_EDGES; d = s;
    }
    s = clampi(s, 0, N_NODES - 1);
    d = clampi(d, 0, N_NODES - 1);
    int pos = atomicAdd(&cur[d], 1);
    if (pos >= 0 && pos < E2) ss[pos] = s;
}

// ----------------------------------------------------- attention kernels ----
// R8 + R10 fast path: wave-per-node layer-1 aggregate, zero barriers.
// deg<=64 (avg deg ~17): pass B reuses pass A's registers (saved logits +
// source), skipping the second random es load + leaky per edge.
__global__ __launch_bounds__(256) void k_aggxw(bf16* __restrict__ A2,
                                               const float* __restrict__ es,
                                               const float* __restrict__ ed,
                                               const int* __restrict__ rp,
                                               const int* __restrict__ ss)
{
    __shared__ float sal[4][4][65];
    __shared__ int   ssrc[4][64];

    const int w    = threadIdx.x >> 6;
    const int lane = threadIdx.x & 63;
    const int n    = blockIdx.x * 4 + w;
    if (n >= N_NODES) return;

    int r0 = clampi(rp[n], 0, E2);
    int r1 = clampi(rp[n + 1], r0, E2);
    const int deg = r1 - r0;

    f32x4 edn = *(const f32x4*)(ed + n * 4);

    // pass A: online softmax stats; save last chunk's logits/source
    float mx[4] = {-1e30f, -1e30f, -1e30f, -1e30f};
    float sm[4] = {0.f, 0.f, 0.f, 0.f};
    float w4s[4];
    int   ssave = 0;
    for (int c0 = 0; c0 < deg; c0 += 64) {
        const int e = c0 + lane;
        const bool val = (e < deg);
        const int s = val ? clampi(ss[r0 + e], 0, N_NODES - 1) : 0;
        f32x4 esv = *(const f32x4*)(es + s * 4);
        float w4[4], mc[4];
#pragma unroll
        for (int h = 0; h < 4; ++h) {
            float v = esv[h] + edn[h];
            v = (v > 0.f) ? v : 0.2f * v;
            w4[h] = val ? v : -1e30f;
            mc[h] = w4[h];
        }
        ssave = s;
#pragma unroll
        for (int h = 0; h < 4; ++h) w4s[h] = w4[h];
#pragma unroll
        for (int off = 32; off; off >>= 1)
#pragma unroll
            for (int h = 0; h < 4; ++h) mc[h] = fmaxf(mc[h], __shfl_xor(mc[h], off));
        float ps[4];
#pragma unroll
        for (int h = 0; h < 4; ++h) {
            float mn = fmaxf(mx[h], mc[h]);
            float f  = __expf(mx[h] - mn);
            ps[h] = __expf(w4[h] - mn);
            mx[h] = mn;
            sm[h] *= f;
        }
#pragma unroll
        for (int off = 32; off; off >>= 1)
#pragma unroll
            for (int h = 0; h < 4; ++h) ps[h] += __shfl_xor(ps[h], off);
#pragma unroll
        for (int h = 0; h < 4; ++h) sm[h] += ps[h];
    }
    float sinv[4];
#pragma unroll
    for (int h = 0; h < 4; ++h) sinv[h] = 1.f / fmaxf(sm[h], 1e-16f);

    const bool single = (deg <= 64);

    // pass B: alpha fill + 8-edge-per-instruction gather
    const int g  = lane >> 3;          // edge slot 0..7
    const int cb = (lane & 7) * 8;     // channel block 0..56
    float acc[4][8];
#pragma unroll
    for (int h = 0; h < 4; ++h)
#pragma unroll
        for (int j = 0; j < 8; ++j) acc[h][j] = 0.f;

    for (int c0 = 0; c0 < deg; c0 += 64) {
        const int ce = min(64, deg - c0);
        int s;
        if (single) {                  // reuse pass-A registers (exp(-huge)=0 masks)
            s = ssave;
#pragma unroll
            for (int h = 0; h < 4; ++h)
                sal[w][h][lane] = __expf(w4s[h] - mx[h]) * sinv[h];
        } else {
            const bool val = (lane < ce);
            const int e = c0 + lane;
            s = val ? clampi(ss[r0 + e], 0, N_NODES - 1) : 0;
            f32x4 esv = *(const f32x4*)(es + s * 4);
#pragma unroll
            for (int h = 0; h < 4; ++h) {
                float v = esv[h] + edn[h];
                v = (v > 0.f) ? v : 0.2f * v;
                sal[w][h][lane] = val ? __expf(v - mx[h]) * sinv[h] : 0.f;
            }
        }
        ssrc[w][lane] = s;
        // wave-synchronous LDS RAW: same-wave ds ops execute in order.
        const int ce8 = (ce + 7) & ~7;
        for (int eb = 0; eb < ce8; eb += 8) {
            const int sg = ssrc[w][eb + g];
            bf16x8 xv = *(const bf16x8*)(A2 + (size_t)sg * KA + 256 + cb);
            float a[4];
#pragma unroll
            for (int h = 0; h < 4; ++h) a[h] = sal[w][h][eb + g];
#pragma unroll
            for (int h = 0; h < 4; ++h)
#pragma unroll
                for (int j = 0; j < 8; ++j) acc[h][j] += a[h] * (float)xv[j];
        }
    }

    // fold across the 8 edge-groups
#pragma unroll
    for (int off = 8; off <= 32; off <<= 1)
#pragma unroll
        for (int h = 0; h < 4; ++h)
#pragma unroll
            for (int j = 0; j < 8; ++j) acc[h][j] += __shfl_xor(acc[h][j], off);

    if (g < 4) {                       // lane group g writes head g
        bf16x8 ov;
#pragma unroll
        for (int j = 0; j < 8; ++j) {
            float v = (g == 0) ? acc[0][j]
                    : (g == 1) ? acc[1][j]
                    : (g == 2) ? acc[2][j] : acc[3][j];
            ov[j] = (bf16)v;
        }
        *(bf16x8*)(A2 + (size_t)n * KA + g * 64 + cb) = ov;
    }
}

// layers 2 logits (wave per node, vectorized)
template <int H, int C>
__global__ __launch_bounds__(256) void k_logits(const bf16* __restrict__ G,
                                                const bf16* __restrict__ as_,
                                                const bf16* __restrict__ ad_,
                                                float* __restrict__ es, float* __restrict__ ed)
{
    const int wave = threadIdx.x >> 6;
    const int lane = threadIdx.x & 63;
    const int n = blockIdx.x * 4 + wave;
    if (n >= N_NODES) return;

#pragma unroll
    for (int h = 0; h < H; ++h) {
        float s = 0.f, d = 0.f;
        if constexpr (C == 256) {
            bf16x4 g  = *(const bf16x4*)(G + (size_t)n * SG + h * 256 + lane * 4);
            bf16x4 av = *(const bf16x4*)(as_ + h * 256 + lane * 4);
            bf16x4 dv = *(const bf16x4*)(ad_ + h * 256 + lane * 4);
#pragma unroll
            for (int j = 0; j < 4; ++j) {
                float gv = (float)g[j];
                s += gv * (float)av[j];
                d += gv * (float)dv[j];
            }
        } else {
            for (int c = lane; c < C; c += 64) {
                float hv = (float)G[(size_t)n * SG + h * C + c];
                s += hv * (float)as_[h * C + c];
                d += hv * (float)ad_[h * C + c];
            }
        }
#pragma unroll
        for (int off = 32; off; off >>= 1) {
            s += __shfl_xor(s, off);
            d += __shfl_xor(d, off);
        }
        if (lane == 0) { es[n * H + h] = s; ed[n * H + h] = d; }
    }
}

// R9: vectorized layer-3 logits (wave per node, 12 ch/lane, LDS atomic fold).
__global__ __launch_bounds__(256) void k_logits3w(const bf16* __restrict__ G,
                                                  const bf16* __restrict__ as_,
                                                  const bf16* __restrict__ ad_,
                                                  float* __restrict__ es,
                                                  float* __restrict__ ed)
{
    __shared__ float sE[4][8], sD[4][8];
    const int w    = threadIdx.x >> 6;
    const int lane = threadIdx.x & 63;
    const int n    = blockIdx.x * 4 + w;
    if (n >= N_NODES) return;

    if (lane < 8) { sE[w][lane] = 0.f; sD[w][lane] = 0.f; }

    const int c0 = lane * 12;          // lanes 0..60 cover 0..731 (726 valid)
    int hA = min(c0 / 121, 5), hB = min((c0 + 11) / 121, 5);
    float sA = 0.f, sB = 0.f, dA = 0.f, dB = 0.f;
    if (c0 < 726) {
        const bf16* gp = G + (size_t)n * SG + c0;
        bf16x4 g0 = *(const bf16x4*)gp;
        bf16x4 g1 = *(const bf16x4*)(gp + 4);
        bf16x4 g2 = *(const bf16x4*)(gp + 8);
        bf16x4 s0 = *(const bf16x4*)(as_ + c0);
        bf16x4 s1 = *(const bf16x4*)(as_ + c0 + 4);
        bf16x4 s2 = *(const bf16x4*)(as_ + c0 + 8);
        bf16x4 d0 = *(const bf16x4*)(ad_ + c0);
        bf16x4 d1 = *(const bf16x4*)(ad_ + c0 + 4);
        bf16x4 d2 = *(const bf16x4*)(ad_ + c0 + 8);
#pragma unroll
        for (int j = 0; j < 12; ++j) {
            int c = c0 + j;
            if (c < 726) {
                float gv = (float)((j < 4) ? g0[j] : (j < 8) ? g1[j - 4] : g2[j - 8]);
                float sv = (float)((j < 4) ? s0[j] : (j < 8) ? s1[j - 4] : s2[j - 8]);
                float dv = (float)((j < 4) ? d0[j] : (j < 8) ? d1[j - 4] : d2[j - 8]);
                if (c / 121 == hA) { sA += gv * sv; dA += gv * dv; }
                else               { sB += gv * sv; dB += gv * dv; }
            }
        }
    }
    // wave-synchronous LDS atomic fold (no barrier: single wave, in-order)
    atomicAdd(&sE[w][hA], sA);
    atomicAdd(&sD[w][hA], dA);
    if (hB != hA) {
        atomicAdd(&sE[w][hB], sB);
        atomicAdd(&sD[w][hB], dB);
    }
    if (lane < 6) {
        es[n * 6 + lane] = sE[w][lane];
        ed[n * 6 + lane] = sD[w][lane];
    }
}

// R7 + R10 fast path: wave-per-node aggregate for layer 2 (H=4, C=256).
__global__ __launch_bounds__(256) void k_aggw(const bf16* __restrict__ G,
                                              const bf16* __restrict__ S,
                                              const float* __restrict__ es,
                                              const float* __restrict__ ed,
                                              const int* __restrict__ rp,
                                              const int* __restrict__ ss,
                                              const bf16* __restrict__ bgat,
                                              const bf16* __restrict__ bskip,
                                              bf16* __restrict__ out, int sout)
{
    __shared__ float sal[4][4][65];    // [wave][head][edge] (+pad)
    __shared__ int   ssrc[4][64];

    const int w    = threadIdx.x >> 6;
    const int lane = threadIdx.x & 63;
    const int n    = blockIdx.x * 4 + w;
    if (n >= N_NODES) return;

    int r0 = clampi(rp[n], 0, E2);
    int r1 = clampi(rp[n + 1], r0, E2);
    const int deg = r1 - r0;

    f32x4 edn = *(const f32x4*)(ed + n * 4);

    // ---- pass A: online max+sum; save last chunk's logits/source
    float mx[4] = {-1e30f, -1e30f, -1e30f, -1e30f};
    float sm[4] = {0.f, 0.f, 0.f, 0.f};
    float w4s[4];
    int   ssave = 0;
    for (int c0 = 0; c0 < deg; c0 += 64) {
        const int e = c0 + lane;
        const bool val = (e < deg);
        const int s = val ? clampi(ss[r0 + e], 0, N_NODES - 1) : 0;
        f32x4 esv = *(const f32x4*)(es + s * 4);
        float w4[4], mc[4];
#pragma unroll
        for (int h = 0; h < 4; ++h) {
            float v = esv[h] + edn[h];
            v = (v > 0.f) ? v : 0.2f * v;
            w4[h] = val ? v : -1e30f;
            mc[h] = w4[h];
        }
        ssave = s;
#pragma unroll
        for (int h = 0; h < 4; ++h) w4s[h] = w4[h];
#pragma unroll
        for (int off = 32; off; off >>= 1)
#pragma unroll
            for (int h = 0; h < 4; ++h) mc[h] = fmaxf(mc[h], __shfl_xor(mc[h], off));
        float ps[4];
#pragma unroll
        for (int h = 0; h < 4; ++h) {
            float mn = fmaxf(mx[h], mc[h]);
            float f  = __expf(mx[h] - mn);
            ps[h] = __expf(w4[h] - mn);
            mx[h] = mn;
            sm[h] *= f;
        }
#pragma unroll
        for (int off = 32; off; off >>= 1)
#pragma unroll
            for (int h = 0; h < 4; ++h) ps[h] += __shfl_xor(ps[h], off);
#pragma unroll
        for (int h = 0; h < 4; ++h) sm[h] += ps[h];
    }
    float sinv[4];
#pragma unroll
    for (int h = 0; h < 4; ++h) sinv[h] = 1.f / fmaxf(sm[h], 1e-16f);

    const bool single = (deg <= 64);

    // ---- pass B: per-chunk alpha fill + gather
    const int myh  = lane >> 4;
    const int c0ch = lane * 16;
    float acc[16];
#pragma unroll
    for (int j = 0; j < 16; ++j) acc[j] = 0.f;

    for (int c0 = 0; c0 < deg; c0 += 64) {
        const int ce = min(64, deg - c0);
        int s;
        if (single) {                  // reuse pass-A registers
            s = ssave;
#pragma unroll
            for (int h = 0; h < 4; ++h)
                sal[w][h][lane] = __expf(w4s[h] - mx[h]) * sinv[h];
        } else {
            const bool val = (lane < ce);
            const int e = c0 + lane;
            s = val ? clampi(ss[r0 + e], 0, N_NODES - 1) : 0;
            f32x4 esv = *(const f32x4*)(es + s * 4);
#pragma unroll
            for (int h = 0; h < 4; ++h) {
                float v = esv[h] + edn[h];
                v = (v > 0.f) ? v : 0.2f * v;
                sal[w][h][lane] = val ? __expf(v - mx[h]) * sinv[h] : 0.f;
            }
        }
        ssrc[w][lane] = s;
        const int ce4 = (ce + 3) & ~3;
        for (int eb = 0; eb < ce4; eb += 4) {
            int sg[4]; float a[4];
#pragma unroll
            for (int p = 0; p < 4; ++p) {
                sg[p] = ssrc[w][eb + p];
                a[p]  = sal[w][myh][eb + p];
            }
            bf16x8 g0[4], g1[4];
#pragma unroll
            for (int p = 0; p < 4; ++p) {
                const bf16* gp = G + (size_t)sg[p] * SG + c0ch;
                g0[p] = *(const bf16x8*)gp;
                g1[p] = *(const bf16x8*)(gp + 8);
            }
#pragma unroll
            for (int p = 0; p < 4; ++p) {
#pragma unroll
                for (int j = 0; j < 8; ++j) acc[j]     += a[p] * (float)g0[p][j];
#pragma unroll
                for (int j = 0; j < 8; ++j) acc[j + 8] += a[p] * (float)g1[p][j];
            }
        }
    }

    // ---- epilogue: + bgat + skip + bskip, ELU, store 32B
    bf16x8 bg0 = *(const bf16x8*)(bgat + c0ch);
    bf16x8 bg1 = *(const bf16x8*)(bgat + c0ch + 8);
    bf16x8 sk0 = *(const bf16x8*)(S + (size_t)n * SG + c0ch);
    bf16x8 sk1 = *(const bf16x8*)(S + (size_t)n * SG + c0ch + 8);
    bf16x8 bs0 = *(const bf16x8*)(bskip + c0ch);
    bf16x8 bs1 = *(const bf16x8*)(bskip + c0ch + 8);
    bf16x8 ov0, ov1;
#pragma unroll
    for (int j = 0; j < 8; ++j) {
        float v = acc[j] + (float)bg0[j] + (float)sk0[j] + (float)bs0[j];
        v = (v > 0.f) ? v : (__expf(v) - 1.f);
        ov0[j] = (bf16)v;
        float u = acc[j + 8] + (float)bg1[j] + (float)sk1[j] + (float)bs1[j];
        u = (u > 0.f) ? u : (__expf(u) - 1.f);
        ov1[j] = (bf16)u;
    }
    *(bf16x8*)(out + (size_t)n * sout + c0ch)     = ov0;
    *(bf16x8*)(out + (size_t)n * sout + c0ch + 8) = ov1;
}

// R8 + R10 fast path: wave-per-node aggregate for layer 3 (H=6, C=121, MEAN).
__global__ __launch_bounds__(256) void k_aggw3(const bf16* __restrict__ G,
                                               const bf16* __restrict__ S,
                                               const float* __restrict__ es,
                                               const float* __restrict__ ed,
                                               const int* __restrict__ rp,
                                               const int* __restrict__ ss,
                                               const bf16* __restrict__ bgat,
                                               const bf16* __restrict__ bskip,
                                               void* __restrict__ out, int sout,
                                               const int* __restrict__ flags)
{
    __shared__ float sal[4][6][65];
    __shared__ int   ssrc[4][64];
    __shared__ float sfold[4][728];

    const int w    = threadIdx.x >> 6;
    const int lane = threadIdx.x & 63;
    const int n    = blockIdx.x * 4 + w;
    if (n >= N_NODES) return;

    int r0 = clampi(rp[n], 0, E2);
    int r1 = clampi(rp[n + 1], r0, E2);
    const int deg = r1 - r0;

    float edn[6];
#pragma unroll
    for (int h = 0; h < 6; ++h) edn[h] = ed[n * 6 + h];

    // pass A: online softmax stats, 6 heads; save last chunk's logits/source
    float mx[6], sm[6], w6s[6];
    int ssave = 0;
#pragma unroll
    for (int h = 0; h < 6; ++h) { mx[h] = -1e30f; sm[h] = 0.f; }
    for (int c0 = 0; c0 < deg; c0 += 64) {
        const int e = c0 + lane;
        const bool val = (e < deg);
        const int s = val ? clampi(ss[r0 + e], 0, N_NODES - 1) : 0;
        const float* ep = es + (size_t)s * 6;
        float w6[6], mc[6];
#pragma unroll
        for (int h = 0; h < 6; ++h) {
            float v = ep[h] + edn[h];
            v = (v > 0.f) ? v : 0.2f * v;
            w6[h] = val ? v : -1e30f;
            mc[h] = w6[h];
        }
        ssave = s;
#pragma unroll
        for (int h = 0; h < 6; ++h) w6s[h] = w6[h];
#pragma unroll
        for (int off = 32; off; off >>= 1)
#pragma unroll
            for (int h = 0; h < 6; ++h) mc[h] = fmaxf(mc[h], __shfl_xor(mc[h], off));
        float ps[6];
#pragma unroll
        for (int h = 0; h < 6; ++h) {
            float mn = fmaxf(mx[h], mc[h]);
            float f  = __expf(mx[h] - mn);
            ps[h] = __expf(w6[h] - mn);
            mx[h] = mn;
            sm[h] *= f;
        }
#pragma unroll
        for (int off = 32; off; off >>= 1)
#pragma unroll
            for (int h = 0; h < 6; ++h) ps[h] += __shfl_xor(ps[h], off);
#pragma unroll
        for (int h = 0; h < 6; ++h) sm[h] += ps[h];
    }
    float sinv[6];
#pragma unroll
    for (int h = 0; h < 6; ++h) sinv[h] = 1.f / fmaxf(sm[h], 1e-16f);

    const bool single = (deg <= 64);

    // pass B: lane owns 12 channels at c0ch; junk channels >=726 are
    // accumulated (in-bounds, finite: skip/pad region) but never written.
    const int c0ch = lane * 12;
    const int hA = min(c0ch / 121, 5);
    const int hB = min((c0ch + 11) / 121, 5);
    bool jA[12];
#pragma unroll
    for (int j = 0; j < 12; ++j) jA[j] = (min((c0ch + j) / 121, 5) == hA);

    float acc[12];
#pragma unroll
    for (int j = 0; j < 12; ++j) acc[j] = 0.f;

    for (int c0 = 0; c0 < deg; c0 += 64) {
        const int ce = min(64, deg - c0);
        int s;
        if (single) {                  // reuse pass-A registers
            s = ssave;
#pragma unroll
            for (int h = 0; h < 6; ++h)
                sal[w][h][lane] = __expf(w6s[h] - mx[h]) * sinv[h];
        } else {
            const bool val = (lane < ce);
            const int e = c0 + lane;
            s = val ? clampi(ss[r0 + e], 0, N_NODES - 1) : 0;
            const float* ep = es + (size_t)s * 6;
#pragma unroll
            for (int h = 0; h < 6; ++h) {
                float v = ep[h] + edn[h];
                v = (v > 0.f) ? v : 0.2f * v;
                sal[w][h][lane] = val ? __expf(v - mx[h]) * sinv[h] : 0.f;
            }
        }
        ssrc[w][lane] = s;
        const int ce4 = (ce + 3) & ~3;
        for (int eb = 0; eb < ce4; eb += 4) {
            int sg[4]; float aL[4], aH[4];
#pragma unroll
            for (int p = 0; p < 4; ++p) {
                sg[p] = ssrc[w][eb + p];
                aL[p] = sal[w][hA][eb + p];
                aH[p] = sal[w][hB][eb + p];
            }
#pragma unroll
            for (int p = 0; p < 4; ++p) {
                const bf16* gp = G + (size_t)sg[p] * SG + c0ch;
                bf16x4 g0 = *(const bf16x4*)gp;
                bf16x4 g1 = *(const bf16x4*)(gp + 4);
                bf16x4 g2 = *(const bf16x4*)(gp + 8);
#pragma unroll
                for (int j = 0; j < 4; ++j) acc[j]     += (jA[j]     ? aL[p] : aH[p]) * (float)g0[j];
#pragma unroll
                for (int j = 0; j < 4; ++j) acc[4 + j] += (jA[4 + j] ? aL[p] : aH[p]) * (float)g1[j];
#pragma unroll
                for (int j = 0; j < 4; ++j) acc[8 + j] += (jA[8 + j] ? aL[p] : aH[p]) * (float)g2[j];
            }
        }
    }

    // head-mean epilogue via wave-local LDS fold (wave-synchronous, in-order)
#pragma unroll
    for (int j = 0; j < 12; ++j) {
        int c = c0ch + j;
        if (c < 726) sfold[w][c] = acc[j];
    }
    const int outbf = flags[1];
    for (int c = lane; c < 121; c += 64) {
        float v = 0.f;
#pragma unroll
        for (int h = 0; h < 6; ++h) v += sfold[w][h * 121 + c];
        v *= (1.f / 6.f);
        v += (float)bgat[c] + (float)S[(size_t)n * SG + c] + (float)bskip[c];
        if (outbf) ((bf16*)out)[(size_t)n * sout + c] = (bf16)v;
        else       ((float*)out)[(size_t)n * sout + c] = v;
    }
}

// ----------------------------------------------------------------- launch ---
extern "C" void kernel_launch(void* const* d_in, const int* in_sizes, int n_in,
                              void* d_out, int out_size, void* d_ws, size_t ws_size,
                              hipStream_t stream)
{
    const void* x   = d_in[0];
    const int*  ei  = (const int*)d_in[1];
    const void* W1  = d_in[2];
    const void* Wl1 = d_in[6];
    const void* W2  = d_in[8];
    const void* Wl2 = d_in[12];
    const void* W3  = d_in[14];
    const void* Wl3 = d_in[18];

    P12 ps;
    ps.s[0] = d_in[3];  ps.s[1] = d_in[4];  ps.s[2] = d_in[5];  ps.s[3] = d_in[7];
    ps.s[4] = d_in[9];  ps.s[5] = d_in[10]; ps.s[6] = d_in[11]; ps.s[7] = d_in[13];
    ps.s[8] = d_in[15]; ps.s[9] = d_in[16]; ps.s[10] = d_in[17]; ps.s[11] = d_in[19];

    char* w = (char*)d_ws;
    auto alloc = [&](size_t bytes) {
        char* p = w;
        w += (bytes + 255) & ~(size_t)255;
        return p;
    };
    int*   flags = (int*)alloc(64);
    int*   cnt   = (int*)alloc((size_t)N_NODES * 4);
    int*   rp    = (int*)alloc((size_t)(N_NODES + 1) * 4);
    int*   cur   = (int*)alloc((size_t)N_NODES * 4);
    int*   ss    = (int*)alloc((size_t)E2 * 4);
    float* es    = (float*)alloc((size_t)N_NODES * 6 * 4);
    float* ed    = (float*)alloc((size_t)N_NODES * 6 * 4);
    bf16*  pool  = (bf16*)alloc((size_t)PO_END * 2);
    float* ws1   = (float*)alloc((size_t)64 * 4 * 4);
    float* wd1   = (float*)alloc((size_t)64 * 4 * 4);
    bf16*  bsum  = (bf16*)alloc((size_t)D1 * 2);
    bf16*  Bt    = (bf16*)alloc((size_t)D1 * KA * 2);        // layer-1 fused B^T
    bf16*  Bt2   = (bf16*)alloc((size_t)NP12 * 1024 * 2);    // layer-2 B^T
    bf16*  Bt3   = (bf16*)alloc((size_t)NP3 * 1024 * 2);     // layer-3 B^T
    bf16*  X     = (bf16*)alloc((size_t)N_NODES * D1 * 2);   // x1/x2
    bf16*  WS    = (bf16*)alloc((size_t)N_NODES * SG * 2);   // GEMM out [gat|skip]
    bf16*  A2    = WS;   // layer-1 A'' [N x KA] aliases WS (dead during layer 1)

    k_detect<<<1, 64, 0, stream>>>(ei, (const unsigned short*)x, flags);

    hipMemsetAsync(cnt, 0, N_NODES * 4, stream);
    k_count<<<(E2 + 255) / 256, 256, 0, stream>>>(ei, cnt, flags);
    k_scan<<<1, 256, 0, stream>>>(cnt, rp, cur);
    k_fill<<<(E2 + 255) / 256, 256, 0, stream>>>(ei, cur, ss, flags);

    const dim3 blk(256);
    const int MT = (N_NODES + 127) / 128;   // 157

    // ---- layer 1: veca -> merged prep (incl wcatT L2/L3) -> aggxw -> GEMM
    k_veca<<<64, 256, 0, stream>>>(W1, ps.s[0], ps.s[1], ps.s[2], ps.s[3],
                                   ws1, wd1, bsum, flags);
    k_prep<<<PB_PADX + PB_WF1 + PB_PAR + PB_LOG1 + PB_WC2 + PB_WC3, 256, 0, stream>>>(
        x, W1, Wl1, W2, Wl2, W3, Wl3, ps, A2, Bt, Bt2, Bt3, pool, ws1, wd1, es, ed, flags);
    k_aggxw<<<N_NODES / 4, 256, 0, stream>>>(A2, es, ed, rp, ss);
    k_gemm<true><<<MT * (D1 / 128), blk, 0, stream>>>(A2, Bt, X, N_NODES, KA, KA, KA, D1,
                                                      MT, D1 / 128, bsum);   // x1 = ELU(...)

    // ---- layer 2: GEMM -> logits -> aggregate
    k_gemm<false><<<MT * (NP12 / 128), blk, 0, stream>>>(X, Bt2, WS, N_NODES, 1024, 1024, 1024, SG,
                                                         MT, NP12 / 128, nullptr);
    k_logits<4, 256><<<N_NODES / 4, 256, 0, stream>>>(WS, pool + PO_A2S, pool + PO_A2D, es, ed);
    k_aggw<<<N_NODES / 4, 256, 0, stream>>>(
        WS, WS + D1, es, ed, rp, ss, pool + PO_B2, pool + PO_BL2, X, D1);

    // ---- layer 3: GEMM -> vectorized logits -> aggregate
    k_gemm<false><<<MT * (NP3 / 128), blk, 0, stream>>>(X, Bt3, WS, N_NODES, 1024, 1024, 1024, SG,
                                                        MT, NP3 / 128, nullptr);
    k_logits3w<<<N_NODES / 4, 256, 0, stream>>>(WS, pool + PO_A3S, pool + PO_A3D, es, ed);
    k_aggw3<<<N_NODES / 4, 256, 0, stream>>>(
        WS, WS + 726, es, ed, rp, ss, pool + PO_B3, pool + PO_BL3, d_out, 121, flags);
}

// Round 13
// 627.048 us; speedup vs baseline: 1.0155x; 1.0066x over previous
//
#include <hip/hip_runtime.h>
#include <hip/hip_bf16.h>
#include <math.h>

typedef __bf16 bf16;
typedef __attribute__((ext_vector_type(4))) __bf16 bf16x4;
typedef __attribute__((ext_vector_type(8))) __bf16 bf16x8;
typedef __attribute__((ext_vector_type(4))) float f32x4;

#define N_NODES 20000
#define N_EDGES 320000
#define E2 (N_EDGES + N_NODES)   // 340000 edges incl self-loops
#define F_IN 50
#define D1 1024                  // H1*C1
#define NP12 2048                // padded GEMM out-cols, layer 2 ([W|Wl])
#define NP3 896                  // padded GEMM out-cols, layer 3 (726+121=847 -> 896)
#define SG 2048                  // row stride of GEMM output buffer
#define KA 320                   // layer-1 fused K: 4*64 aggx + 64 x

// params pool element offsets (bf16 pool)
#define PO_A1S 0
#define PO_A1D 1024
#define PO_B1  2048
#define PO_BL1 3072
#define PO_A2S 4096
#define PO_A2D 5120
#define PO_B2  6144
#define PO_BL2 7168
#define PO_A3S 8192
#define PO_A3D 8918
#define PO_B3  9644
#define PO_BL3 9765
#define PO_END 9886

// k_prep block-range sizes
#define PB_PADX  5000            // N_NODES*64/256
#define PB_WF1   1280            // D1*KA/256
#define PB_PAR   39              // ceil(PO_END/256)
#define PB_LOG1  5000            // N_NODES/4
#define PB_WC2   512             // wcatT layer 2: 16 x 32
#define PB_WC3   224             // wcatT layer 3: 16 x 14

__device__ __forceinline__ int clampi(int v, int lo, int hi)
{
    return v < lo ? lo : (v > hi ? hi : v);
}

__device__ __forceinline__ float loadf(const void* p, long idx, int isb)
{
    return isb ? (float)((const bf16*)p)[idx] : ((const float*)p)[idx];
}

__device__ __forceinline__ int loadei(const int* ei, long idx, int i64)
{
    return i64 ? ei[2 * idx] : ei[idx];
}

// --------------------------------------------------------------- detect -----
__global__ void k_detect(const int* __restrict__ ei,
                         const unsigned short* __restrict__ xw,
                         int* __restrict__ flags)
{
    if (blockIdx.x != 0 || threadIdx.x != 0) return;
    int allz = 1;
    for (int i = 0; i < 128; ++i)
        if (ei[2 * i + 1] != 0) { allz = 0; break; }
    int inr = 0;
    for (int i = 0; i < 128; ++i) {
        int e = (xw[2 * i] >> 7) & 0xFF;
        if (e >= 100 && e <= 140) inr++;
    }
    flags[0] = allz;
    flags[1] = (inr >= 64) ? 1 : 0;
}

// ---------------------------------------------------------------- GEMM ------
// m97-style 128x128 tile, BK=64. BACT: fused bias+ELU epilogue.
template <bool BACT>
__global__ __launch_bounds__(256) void k_gemm(const bf16* __restrict__ A,
                                              const bf16* __restrict__ Bt,
                                              bf16* __restrict__ C,
                                              int M, int K, int lda, int ldb, int ldc,
                                              int mtiles, int ntiles,
                                              const bf16* __restrict__ bias)
{
    __shared__ bf16 As[128 * 64];
    __shared__ bf16 Bs[128 * 64];

    int id = blockIdx.x;
    int gfull = mtiles >> 3;
    int base  = gfull * 8 * ntiles;
    int x, y;
    if (id < base) {
        int gsz = 8 * ntiles;
        int g = id / gsz;
        int r = id - g * gsz;
        x = g * 8 + (r & 7);
        y = r >> 3;
    } else {
        int rem = mtiles - (gfull << 3);
        int r = id - base;
        x = (gfull << 3) + r % rem;
        y = r / rem;
    }
    const int m0 = x * 128;
    const int n0 = y * 128;

    const int tid  = threadIdx.x;
    const int wave = tid >> 6;
    const int lane = tid & 63;
    const int wm   = (wave >> 1) * 64;
    const int wn   = (wave & 1) * 64;
    const int frow  = lane & 15;

    const int srow = wave * 32 + (lane >> 3);
    const int scol = (((lane & 7) ^ (lane >> 3)) * 8);

    f32x4 acc[4][4];
#pragma unroll
    for (int i = 0; i < 4; ++i)
#pragma unroll
        for (int j = 0; j < 4; ++j)
#pragma unroll
            for (int r = 0; r < 4; ++r) acc[i][j][r] = 0.f;

    for (int k0 = 0; k0 < K; k0 += 64) {
#pragma unroll
        for (int i = 0; i < 4; ++i) {
            int ra = srow + i * 8;
            int ga = m0 + ra; if (ga > M - 1) ga = M - 1;   // junk rows -> discarded C rows
            __builtin_amdgcn_global_load_lds(
                (const __attribute__((address_space(1))) void*)(A + (size_t)ga * lda + k0 + scol),
                (__attribute__((address_space(3))) void*)(As + wave * 2048 + i * 512),
                16, 0, 0);
            int gb = n0 + ra;
            __builtin_amdgcn_global_load_lds(
                (const __attribute__((address_space(1))) void*)(Bt + (size_t)gb * ldb + k0 + scol),
                (__attribute__((address_space(3))) void*)(Bs + wave * 2048 + i * 512),
                16, 0, 0);
        }
        __syncthreads();
#pragma unroll
        for (int kk = 0; kk < 2; ++kk) {
            const int coff = (((kk * 4 + (lane >> 4)) ^ (frow & 7)) << 3);
            bf16x8 af[4], bfr[4];
#pragma unroll
            for (int i = 0; i < 4; ++i) {
                af[i]  = *(const bf16x8*)(As + (wm + i * 16 + frow) * 64 + coff);
                bfr[i] = *(const bf16x8*)(Bs + (wn + i * 16 + frow) * 64 + coff);
            }
#pragma unroll
            for (int i = 0; i < 4; ++i)
#pragma unroll
                for (int j = 0; j < 4; ++j)
                    acc[i][j] = __builtin_amdgcn_mfma_f32_16x16x32_bf16(af[i], bfr[j], acc[i][j], 0, 0, 0);
        }
        __syncthreads();
    }

#pragma unroll
    for (int i = 0; i < 4; ++i) {
#pragma unroll
        for (int j = 0; j < 4; ++j) {
            int rbase = m0 + wm + i * 16 + (lane >> 4) * 4;
            int col   = n0 + wn + j * 16 + frow;
            if constexpr (BACT) {
                float bv = (float)bias[col];
#pragma unroll
                for (int r = 0; r < 4; ++r) {
                    int row = rbase + r;
                    if (row < M) {
                        float v = acc[i][j][r] + bv;
                        v = (v > 0.f) ? v : (__expf(v) - 1.f);
                        C[(size_t)row * ldc + col] = (bf16)v;
                    }
                }
            } else {
#pragma unroll
                for (int r = 0; r < 4; ++r) {
                    int row = rbase + r;
                    if (row < M) C[(size_t)row * ldc + col] = (bf16)acc[i][j][r];
                }
            }
        }
    }
}

// ------------------------------------------------------------ prep kernels --
// ws[k][h] = sum_c W1[k, h*256+c]*a1s[h,c]; wd likewise; bsum = b1+bl1.
__global__ __launch_bounds__(256) void k_veca(const void* __restrict__ W1,
                                              const void* __restrict__ a1s,
                                              const void* __restrict__ a1d,
                                              const void* __restrict__ b1,
                                              const void* __restrict__ bl1,
                                              float* __restrict__ ws, float* __restrict__ wd,
                                              bf16* __restrict__ bsum,
                                              const int* __restrict__ flags)
{
    const int isb = flags[1];
    const int k = blockIdx.x;          // 0..63
    const int h = threadIdx.x >> 6;
    const int c0 = threadIdx.x & 63;
    float s = 0.f, d = 0.f;
    if (k < F_IN) {
        for (int c = c0; c < 256; c += 64) {
            float wv = loadf(W1, (long)k * D1 + h * 256 + c, isb);
            s += wv * loadf(a1s, h * 256 + c, isb);
            d += wv * loadf(a1d, h * 256 + c, isb);
        }
    }
#pragma unroll
    for (int off = 32; off; off >>= 1) {
        s += __shfl_xor(s, off);
        d += __shfl_xor(d, off);
    }
    if (c0 == 0) { ws[k * 4 + h] = s; wd[k * 4 + h] = d; }
    if (k < 4) {
        int j = k * 256 + threadIdx.x;
        bsum[j] = (bf16)(loadf(b1, j, isb) + loadf(bl1, j, isb));
    }
}

struct P12 { const void* s[12]; };

// merged prep: padx | wfuse1 | params | logits1-from-x | wcatT-L2 | wcatT-L3.
__global__ __launch_bounds__(256) void k_prep(const void* __restrict__ x,
                                              const void* __restrict__ W1,
                                              const void* __restrict__ Wl1,
                                              const void* __restrict__ W2,
                                              const void* __restrict__ Wl2,
                                              const void* __restrict__ W3,
                                              const void* __restrict__ Wl3,
                                              P12 ps,
                                              bf16* __restrict__ A2,
                                              bf16* __restrict__ Bt,
                                              bf16* __restrict__ Bt2,
                                              bf16* __restrict__ Bt3,
                                              bf16* __restrict__ pool,
                                              const float* __restrict__ ws,
                                              const float* __restrict__ wd,
                                              float* __restrict__ es,
                                              float* __restrict__ ed,
                                              const int* __restrict__ flags)
{
    __shared__ bf16 T[64][65];
    const int isb = flags[1];
    int b = blockIdx.x;

    if (b < PB_PADX) {                       // ---- x -> A2[n*KA + 256 + k]
        int idx = b * 256 + threadIdx.x;
        int n = idx >> 6, k = idx & 63;
        A2[(size_t)n * KA + 256 + k] = (k < F_IN) ? (bf16)loadf(x, (long)n * F_IN + k, isb)
                                                  : (bf16)0.f;
        return;
    }
    b -= PB_PADX;

    if (b < PB_WF1) {                        // ---- fused layer-1 B^T
        int idx = b * 256 + threadIdx.x;
        int j = idx / KA;
        int kp = idx - j * KA;
        float v = 0.f;
        if (kp < 256) {
            int hp = kp >> 6, k = kp & 63;
            if ((j >> 8) == hp && k < F_IN) v = loadf(W1, (long)k * D1 + j, isb);
        } else {
            int k = kp - 256;
            if (k < F_IN) v = loadf(Wl1, (long)k * D1 + j, isb);
        }
        Bt[idx] = (bf16)v;
        return;
    }
    b -= PB_WF1;

    if (b < PB_PAR) {                        // ---- params pool
        const int off[13] = {PO_A1S, PO_A1D, PO_B1, PO_BL1, PO_A2S, PO_A2D, PO_B2,
                             PO_BL2, PO_A3S, PO_A3D, PO_B3, PO_BL3, PO_END};
        int idx = b * 256 + threadIdx.x;
        if (idx < PO_END) {
            int seg = 0;
            while (idx >= off[seg + 1]) seg++;
            pool[idx] = (bf16)loadf(ps.s[seg], idx - off[seg], isb);
        }
        return;
    }
    b -= PB_PAR;

    if (b < PB_LOG1) {                       // ---- layer-1 logits from x
        const int wave = threadIdx.x >> 6;
        const int lane = threadIdx.x & 63;
        const int n = b * 4 + wave;
        if (n >= N_NODES) return;
        float xv = (lane < F_IN) ? loadf(x, (long)n * F_IN + lane, isb) : 0.f;
        f32x4 wsv = *(const f32x4*)(ws + lane * 4);
        f32x4 wdv = *(const f32x4*)(wd + lane * 4);
        float s[4], d[4];
#pragma unroll
        for (int h = 0; h < 4; ++h) { s[h] = xv * wsv[h]; d[h] = xv * wdv[h]; }
#pragma unroll
        for (int off = 32; off; off >>= 1)
#pragma unroll
            for (int h = 0; h < 4; ++h) {
                s[h] += __shfl_xor(s[h], off);
                d[h] += __shfl_xor(d[h], off);
            }
        if (lane == 0) {
#pragma unroll
            for (int h = 0; h < 4; ++h) { es[n * 4 + h] = s[h]; ed[n * 4 + h] = d[h]; }
        }
        return;
    }
    b -= PB_LOG1;

    // ---- wcatT ranges: Bt*[n][k] = [Wa | Wb | 0](k, n)
    const void* Wa; const void* Wb; bf16* Bo; int split, da, db, bx, by;
    if (b < PB_WC2) {
        Wa = W2; Wb = Wl2; Bo = Bt2; split = 1024; da = 1024; db = 1024;
        bx = b & 15; by = b >> 4;
    } else {
        b -= PB_WC2;
        Wa = W3; Wb = Wl3; Bo = Bt3; split = 726; da = 726; db = 121;
        bx = b % 16; by = b / 16;
    }
    {
        const int k0 = bx * 64;
        const int n0 = by * 64;
        const int r = threadIdx.x >> 6;
        const int c = threadIdx.x & 63;
        const int n = n0 + c;
#pragma unroll
        for (int kk = 0; kk < 16; ++kk) {
            int k = k0 + r + kk * 4;
            float v = 0.f;
            if (n < split)           v = loadf(Wa, (long)k * da + n, isb);
            else if (n < split + db) v = loadf(Wb, (long)k * db + (n - split), isb);
            T[r + kk * 4][c] = (bf16)v;
        }
        __syncthreads();
#pragma unroll
        for (int kk = 0; kk < 16; ++kk) {
            int nn = r + kk * 4;
            Bo[(size_t)(n0 + nn) * 1024 + k0 + c] = T[c][nn];
        }
    }
}

// ------------------------------------------------------------- CSR build ----
__global__ void k_count(const int* __restrict__ ei, int* __restrict__ cnt,
                        const int* __restrict__ flags)
{
    int e = blockIdx.x * 256 + threadIdx.x;
    if (e >= E2) return;
    int i64 = flags[0];
    int d = (e < N_EDGES) ? loadei(ei, (long)N_EDGES + e, i64) : (e - N_EDGES);
    d = clampi(d, 0, N_NODES - 1);
    atomicAdd(&cnt[d], 1);
}

__global__ __launch_bounds__(256) void k_scan(const int* __restrict__ cnt,
                                              int* __restrict__ rp,
                                              int* __restrict__ cur)
{
    __shared__ int ssum[256];
    int tid = threadIdx.x;
    const int chunk = (N_NODES + 255) / 256;
    int lo = tid * chunk;
    int hi = lo + chunk; if (hi > N_NODES) hi = N_NODES;
    int s = 0;
    for (int i = lo; i < hi; ++i) s += cnt[i];
    ssum[tid] = s;
    __syncthreads();
    if (tid == 0) {
        int run = 0;
        for (int i = 0; i < 256; ++i) { int t = ssum[i]; ssum[i] = run; run += t; }
        rp[N_NODES] = run;
    }
    __syncthreads();
    int run = ssum[tid];
    for (int i = lo; i < hi; ++i) { rp[i] = run; cur[i] = run; run += cnt[i]; }
}

__global__ void k_fill(const int* __restrict__ ei, int* __restrict__ cur,
                       int* __restrict__ ss, const int* __restrict__ flags)
{
    int e = blockIdx.x * 256 + threadIdx.x;
    if (e >= E2) return;
    int i64 = flags[0];
    int s, d;
    if (e < N_EDGES) {
        s = loadei(ei, e, i64);
        d = loadei(ei, (long)N_EDGES + e, i64);
    } else {
        s = e - N_EDGES; d = s;
    }
    s = clampi(s, 0, N_NODES - 1);
    d = clampi(d, 0, N_NODES - 1);
    int pos = atomicAdd(&cur[d], 1);
    if (pos >= 0 && pos < E2) ss[pos] = s;
}

// ----------------------------------------------------- attention kernels ----
// R8 + R10 fast path: wave-per-node layer-1 aggregate, zero barriers.
__global__ __launch_bounds__(256) void k_aggxw(bf16* __restrict__ A2,
                                               const float* __restrict__ es,
                                               const float* __restrict__ ed,
                                               const int* __restrict__ rp,
                                               const int* __restrict__ ss)
{
    __shared__ float sal[4][4][65];
    __shared__ int   ssrc[4][64];

    const int w    = threadIdx.x >> 6;
    const int lane = threadIdx.x & 63;
    const int n    = blockIdx.x * 4 + w;
    if (n >= N_NODES) return;

    int r0 = clampi(rp[n], 0, E2);
    int r1 = clampi(rp[n + 1], r0, E2);
    const int deg = r1 - r0;

    f32x4 edn = *(const f32x4*)(ed + n * 4);

    // pass A: online softmax stats; save last chunk's logits/source
    float mx[4] = {-1e30f, -1e30f, -1e30f, -1e30f};
    float sm[4] = {0.f, 0.f, 0.f, 0.f};
    float w4s[4];
    int   ssave = 0;
    for (int c0 = 0; c0 < deg; c0 += 64) {
        const int e = c0 + lane;
        const bool val = (e < deg);
        const int s = val ? clampi(ss[r0 + e], 0, N_NODES - 1) : 0;
        f32x4 esv = *(const f32x4*)(es + s * 4);
        float w4[4], mc[4];
#pragma unroll
        for (int h = 0; h < 4; ++h) {
            float v = esv[h] + edn[h];
            v = (v > 0.f) ? v : 0.2f * v;
            w4[h] = val ? v : -1e30f;
            mc[h] = w4[h];
        }
        ssave = s;
#pragma unroll
        for (int h = 0; h < 4; ++h) w4s[h] = w4[h];
#pragma unroll
        for (int off = 32; off; off >>= 1)
#pragma unroll
            for (int h = 0; h < 4; ++h) mc[h] = fmaxf(mc[h], __shfl_xor(mc[h], off));
        float ps[4];
#pragma unroll
        for (int h = 0; h < 4; ++h) {
            float mn = fmaxf(mx[h], mc[h]);
            float f  = __expf(mx[h] - mn);
            ps[h] = __expf(w4[h] - mn);
            mx[h] = mn;
            sm[h] *= f;
        }
#pragma unroll
        for (int off = 32; off; off >>= 1)
#pragma unroll
            for (int h = 0; h < 4; ++h) ps[h] += __shfl_xor(ps[h], off);
#pragma unroll
        for (int h = 0; h < 4; ++h) sm[h] += ps[h];
    }
    float sinv[4];
#pragma unroll
    for (int h = 0; h < 4; ++h) sinv[h] = 1.f / fmaxf(sm[h], 1e-16f);

    const bool single = (deg <= 64);

    // pass B: alpha fill + 8-edge-per-instruction gather
    const int g  = lane >> 3;          // edge slot 0..7
    const int cb = (lane & 7) * 8;     // channel block 0..56
    float acc[4][8];
#pragma unroll
    for (int h = 0; h < 4; ++h)
#pragma unroll
        for (int j = 0; j < 8; ++j) acc[h][j] = 0.f;

    for (int c0 = 0; c0 < deg; c0 += 64) {
        const int ce = min(64, deg - c0);
        int s;
        if (single) {                  // reuse pass-A registers (exp(-huge)=0 masks)
            s = ssave;
#pragma unroll
            for (int h = 0; h < 4; ++h)
                sal[w][h][lane] = __expf(w4s[h] - mx[h]) * sinv[h];
        } else {
            const bool val = (lane < ce);
            const int e = c0 + lane;
            s = val ? clampi(ss[r0 + e], 0, N_NODES - 1) : 0;
            f32x4 esv = *(const f32x4*)(es + s * 4);
#pragma unroll
            for (int h = 0; h < 4; ++h) {
                float v = esv[h] + edn[h];
                v = (v > 0.f) ? v : 0.2f * v;
                sal[w][h][lane] = val ? __expf(v - mx[h]) * sinv[h] : 0.f;
            }
        }
        ssrc[w][lane] = s;
        // wave-synchronous LDS RAW: same-wave ds ops execute in order.
        const int ce8 = (ce + 7) & ~7;
        for (int eb = 0; eb < ce8; eb += 8) {
            const int sg = ssrc[w][eb + g];
            bf16x8 xv = *(const bf16x8*)(A2 + (size_t)sg * KA + 256 + cb);
            float a[4];
#pragma unroll
            for (int h = 0; h < 4; ++h) a[h] = sal[w][h][eb + g];
#pragma unroll
            for (int h = 0; h < 4; ++h)
#pragma unroll
                for (int j = 0; j < 8; ++j) acc[h][j] += a[h] * (float)xv[j];
        }
    }

    // fold across the 8 edge-groups
#pragma unroll
    for (int off = 8; off <= 32; off <<= 1)
#pragma unroll
        for (int h = 0; h < 4; ++h)
#pragma unroll
            for (int j = 0; j < 8; ++j) acc[h][j] += __shfl_xor(acc[h][j], off);

    if (g < 4) {                       // lane group g writes head g
        bf16x8 ov;
#pragma unroll
        for (int j = 0; j < 8; ++j) {
            float v = (g == 0) ? acc[0][j]
                    : (g == 1) ? acc[1][j]
                    : (g == 2) ? acc[2][j] : acc[3][j];
            ov[j] = (bf16)v;
        }
        *(bf16x8*)(A2 + (size_t)n * KA + g * 64 + cb) = ov;
    }
}

// layers 2 logits (wave per node, vectorized)
template <int H, int C>
__global__ __launch_bounds__(256) void k_logits(const bf16* __restrict__ G,
                                                const bf16* __restrict__ as_,
                                                const bf16* __restrict__ ad_,
                                                float* __restrict__ es, float* __restrict__ ed)
{
    const int wave = threadIdx.x >> 6;
    const int lane = threadIdx.x & 63;
    const int n = blockIdx.x * 4 + wave;
    if (n >= N_NODES) return;

#pragma unroll
    for (int h = 0; h < H; ++h) {
        float s = 0.f, d = 0.f;
        if constexpr (C == 256) {
            bf16x4 g  = *(const bf16x4*)(G + (size_t)n * SG + h * 256 + lane * 4);
            bf16x4 av = *(const bf16x4*)(as_ + h * 256 + lane * 4);
            bf16x4 dv = *(const bf16x4*)(ad_ + h * 256 + lane * 4);
#pragma unroll
            for (int j = 0; j < 4; ++j) {
                float gv = (float)g[j];
                s += gv * (float)av[j];
                d += gv * (float)dv[j];
            }
        } else {
            for (int c = lane; c < C; c += 64) {
                float hv = (float)G[(size_t)n * SG + h * C + c];
                s += hv * (float)as_[h * C + c];
                d += hv * (float)ad_[h * C + c];
            }
        }
#pragma unroll
        for (int off = 32; off; off >>= 1) {
            s += __shfl_xor(s, off);
            d += __shfl_xor(d, off);
        }
        if (lane == 0) { es[n * H + h] = s; ed[n * H + h] = d; }
    }
}

// R9: vectorized layer-3 logits (wave per node, 12 ch/lane, LDS atomic fold).
__global__ __launch_bounds__(256) void k_logits3w(const bf16* __restrict__ G,
                                                  const bf16* __restrict__ as_,
                                                  const bf16* __restrict__ ad_,
                                                  float* __restrict__ es,
                                                  float* __restrict__ ed)
{
    __shared__ float sE[4][8], sD[4][8];
    const int w    = threadIdx.x >> 6;
    const int lane = threadIdx.x & 63;
    const int n    = blockIdx.x * 4 + w;
    if (n >= N_NODES) return;

    if (lane < 8) { sE[w][lane] = 0.f; sD[w][lane] = 0.f; }

    const int c0 = lane * 12;          // lanes 0..60 cover 0..731 (726 valid)
    int hA = min(c0 / 121, 5), hB = min((c0 + 11) / 121, 5);
    float sA = 0.f, sB = 0.f, dA = 0.f, dB = 0.f;
    if (c0 < 726) {
        const bf16* gp = G + (size_t)n * SG + c0;
        bf16x4 g0 = *(const bf16x4*)gp;
        bf16x4 g1 = *(const bf16x4*)(gp + 4);
        bf16x4 g2 = *(const bf16x4*)(gp + 8);
        bf16x4 s0 = *(const bf16x4*)(as_ + c0);
        bf16x4 s1 = *(const bf16x4*)(as_ + c0 + 4);
        bf16x4 s2 = *(const bf16x4*)(as_ + c0 + 8);
        bf16x4 d0 = *(const bf16x4*)(ad_ + c0);
        bf16x4 d1 = *(const bf16x4*)(ad_ + c0 + 4);
        bf16x4 d2 = *(const bf16x4*)(ad_ + c0 + 8);
#pragma unroll
        for (int j = 0; j < 12; ++j) {
            int c = c0 + j;
            if (c < 726) {
                float gv = (float)((j < 4) ? g0[j] : (j < 8) ? g1[j - 4] : g2[j - 8]);
                float sv = (float)((j < 4) ? s0[j] : (j < 8) ? s1[j - 4] : s2[j - 8]);
                float dv = (float)((j < 4) ? d0[j] : (j < 8) ? d1[j - 4] : d2[j - 8]);
                if (c / 121 == hA) { sA += gv * sv; dA += gv * dv; }
                else               { sB += gv * sv; dB += gv * dv; }
            }
        }
    }
    // wave-synchronous LDS atomic fold (no barrier: single wave, in-order)
    atomicAdd(&sE[w][hA], sA);
    atomicAdd(&sD[w][hA], dA);
    if (hB != hA) {
        atomicAdd(&sE[w][hB], sB);
        atomicAdd(&sD[w][hB], dB);
    }
    if (lane < 6) {
        es[n * 6 + lane] = sE[w][lane];
        ed[n * 6 + lane] = sD[w][lane];
    }
}

// R7 + R10 fast path + R11 8-deep batch: wave-per-node aggregate, layer 2.
// Pass B keeps 16 x 16B loads in flight per wave (was 8) — the kernel
// is gather-latency-bound (R11 counters: VALU 33%, HBM 46%, dur flat).
__global__ __launch_bounds__(256) void k_aggw(const bf16* __restrict__ G,
                                              const bf16* __restrict__ S,
                                              const float* __restrict__ es,
                                              const float* __restrict__ ed,
                                              const int* __restrict__ rp,
                                              const int* __restrict__ ss,
                                              const bf16* __restrict__ bgat,
                                              const bf16* __restrict__ bskip,
                                              bf16* __restrict__ out, int sout)
{
    __shared__ float sal[4][4][65];    // [wave][head][edge] (+pad)
    __shared__ int   ssrc[4][64];

    const int w    = threadIdx.x >> 6;
    const int lane = threadIdx.x & 63;
    const int n    = blockIdx.x * 4 + w;
    if (n >= N_NODES) return;

    int r0 = clampi(rp[n], 0, E2);
    int r1 = clampi(rp[n + 1], r0, E2);
    const int deg = r1 - r0;

    f32x4 edn = *(const f32x4*)(ed + n * 4);

    // ---- pass A: online max+sum; save last chunk's logits/source
    float mx[4] = {-1e30f, -1e30f, -1e30f, -1e30f};
    float sm[4] = {0.f, 0.f, 0.f, 0.f};
    float w4s[4];
    int   ssave = 0;
    for (int c0 = 0; c0 < deg; c0 += 64) {
        const int e = c0 + lane;
        const bool val = (e < deg);
        const int s = val ? clampi(ss[r0 + e], 0, N_NODES - 1) : 0;
        f32x4 esv = *(const f32x4*)(es + s * 4);
        float w4[4], mc[4];
#pragma unroll
        for (int h = 0; h < 4; ++h) {
            float v = esv[h] + edn[h];
            v = (v > 0.f) ? v : 0.2f * v;
            w4[h] = val ? v : -1e30f;
            mc[h] = w4[h];
        }
        ssave = s;
#pragma unroll
        for (int h = 0; h < 4; ++h) w4s[h] = w4[h];
#pragma unroll
        for (int off = 32; off; off >>= 1)
#pragma unroll
            for (int h = 0; h < 4; ++h) mc[h] = fmaxf(mc[h], __shfl_xor(mc[h], off));
        float ps[4];
#pragma unroll
        for (int h = 0; h < 4; ++h) {
            float mn = fmaxf(mx[h], mc[h]);
            float f  = __expf(mx[h] - mn);
            ps[h] = __expf(w4[h] - mn);
            mx[h] = mn;
            sm[h] *= f;
        }
#pragma unroll
        for (int off = 32; off; off >>= 1)
#pragma unroll
            for (int h = 0; h < 4; ++h) ps[h] += __shfl_xor(ps[h], off);
#pragma unroll
        for (int h = 0; h < 4; ++h) sm[h] += ps[h];
    }
    float sinv[4];
#pragma unroll
    for (int h = 0; h < 4; ++h) sinv[h] = 1.f / fmaxf(sm[h], 1e-16f);

    const bool single = (deg <= 64);

    // ---- pass B: per-chunk alpha fill + 8-deep gather
    const int myh  = lane >> 4;
    const int c0ch = lane * 16;
    float acc[16];
#pragma unroll
    for (int j = 0; j < 16; ++j) acc[j] = 0.f;

    for (int c0 = 0; c0 < deg; c0 += 64) {
        const int ce = min(64, deg - c0);
        int s;
        if (single) {                  // reuse pass-A registers
            s = ssave;
#pragma unroll
            for (int h = 0; h < 4; ++h)
                sal[w][h][lane] = __expf(w4s[h] - mx[h]) * sinv[h];
        } else {
            const bool val = (lane < ce);
            const int e = c0 + lane;
            s = val ? clampi(ss[r0 + e], 0, N_NODES - 1) : 0;
            f32x4 esv = *(const f32x4*)(es + s * 4);
#pragma unroll
            for (int h = 0; h < 4; ++h) {
                float v = esv[h] + edn[h];
                v = (v > 0.f) ? v : 0.2f * v;
                sal[w][h][lane] = val ? __expf(v - mx[h]) * sinv[h] : 0.f;
            }
        }
        ssrc[w][lane] = s;
        const int ce8 = (ce + 7) & ~7;
        for (int eb = 0; eb < ce8; eb += 8) {
            int sg[8]; float a[8];
#pragma unroll
            for (int p = 0; p < 8; ++p) {
                sg[p] = ssrc[w][eb + p];
                a[p]  = sal[w][myh][eb + p];
            }
            bf16x8 g0[8], g1[8];
#pragma unroll
            for (int p = 0; p < 8; ++p) {
                const bf16* gp = G + (size_t)sg[p] * SG + c0ch;
                g0[p] = *(const bf16x8*)gp;
                g1[p] = *(const bf16x8*)(gp + 8);
            }
#pragma unroll
            for (int p = 0; p < 8; ++p) {
#pragma unroll
                for (int j = 0; j < 8; ++j) acc[j]     += a[p] * (float)g0[p][j];
#pragma unroll
                for (int j = 0; j < 8; ++j) acc[j + 8] += a[p] * (float)g1[p][j];
            }
        }
    }

    // ---- epilogue: + bgat + skip + bskip, ELU, store 32B
    bf16x8 bg0 = *(const bf16x8*)(bgat + c0ch);
    bf16x8 bg1 = *(const bf16x8*)(bgat + c0ch + 8);
    bf16x8 sk0 = *(const bf16x8*)(S + (size_t)n * SG + c0ch);
    bf16x8 sk1 = *(const bf16x8*)(S + (size_t)n * SG + c0ch + 8);
    bf16x8 bs0 = *(const bf16x8*)(bskip + c0ch);
    bf16x8 bs1 = *(const bf16x8*)(bskip + c0ch + 8);
    bf16x8 ov0, ov1;
#pragma unroll
    for (int j = 0; j < 8; ++j) {
        float v = acc[j] + (float)bg0[j] + (float)sk0[j] + (float)bs0[j];
        v = (v > 0.f) ? v : (__expf(v) - 1.f);
        ov0[j] = (bf16)v;
        float u = acc[j + 8] + (float)bg1[j] + (float)sk1[j] + (float)bs1[j];
        u = (u > 0.f) ? u : (__expf(u) - 1.f);
        ov1[j] = (bf16)u;
    }
    *(bf16x8*)(out + (size_t)n * sout + c0ch)     = ov0;
    *(bf16x8*)(out + (size_t)n * sout + c0ch + 8) = ov1;
}

// R8 + R10 fast path: wave-per-node aggregate for layer 3 (H=6, C=121, MEAN).
__global__ __launch_bounds__(256) void k_aggw3(const bf16* __restrict__ G,
                                               const bf16* __restrict__ S,
                                               const float* __restrict__ es,
                                               const float* __restrict__ ed,
                                               const int* __restrict__ rp,
                                               const int* __restrict__ ss,
                                               const bf16* __restrict__ bgat,
                                               const bf16* __restrict__ bskip,
                                               void* __restrict__ out, int sout,
                                               const int* __restrict__ flags)
{
    __shared__ float sal[4][6][65];
    __shared__ int   ssrc[4][64];
    __shared__ float sfold[4][728];

    const int w    = threadIdx.x >> 6;
    const int lane = threadIdx.x & 63;
    const int n    = blockIdx.x * 4 + w;
    if (n >= N_NODES) return;

    int r0 = clampi(rp[n], 0, E2);
    int r1 = clampi(rp[n + 1], r0, E2);
    const int deg = r1 - r0;

    float edn[6];
#pragma unroll
    for (int h = 0; h < 6; ++h) edn[h] = ed[n * 6 + h];

    // pass A: online softmax stats, 6 heads; save last chunk's logits/source
    float mx[6], sm[6], w6s[6];
    int ssave = 0;
#pragma unroll
    for (int h = 0; h < 6; ++h) { mx[h] = -1e30f; sm[h] = 0.f; }
    for (int c0 = 0; c0 < deg; c0 += 64) {
        const int e = c0 + lane;
        const bool val = (e < deg);
        const int s = val ? clampi(ss[r0 + e], 0, N_NODES - 1) : 0;
        const float* ep = es + (size_t)s * 6;
        float w6[6], mc[6];
#pragma unroll
        for (int h = 0; h < 6; ++h) {
            float v = ep[h] + edn[h];
            v = (v > 0.f) ? v : 0.2f * v;
            w6[h] = val ? v : -1e30f;
            mc[h] = w6[h];
        }
        ssave = s;
#pragma unroll
        for (int h = 0; h < 6; ++h) w6s[h] = w6[h];
#pragma unroll
        for (int off = 32; off; off >>= 1)
#pragma unroll
            for (int h = 0; h < 6; ++h) mc[h] = fmaxf(mc[h], __shfl_xor(mc[h], off));
        float ps[6];
#pragma unroll
        for (int h = 0; h < 6; ++h) {
            float mn = fmaxf(mx[h], mc[h]);
            float f  = __expf(mx[h] - mn);
            ps[h] = __expf(w6[h] - mn);
            mx[h] = mn;
            sm[h] *= f;
        }
#pragma unroll
        for (int off = 32; off; off >>= 1)
#pragma unroll
            for (int h = 0; h < 6; ++h) ps[h] += __shfl_xor(ps[h], off);
#pragma unroll
        for (int h = 0; h < 6; ++h) sm[h] += ps[h];
    }
    float sinv[6];
#pragma unroll
    for (int h = 0; h < 6; ++h) sinv[h] = 1.f / fmaxf(sm[h], 1e-16f);

    const bool single = (deg <= 64);

    // pass B: lane owns 12 channels at c0ch; junk channels >=726 are
    // accumulated (in-bounds, finite: skip/pad region) but never written.
    const int c0ch = lane * 12;
    const int hA = min(c0ch / 121, 5);
    const int hB = min((c0ch + 11) / 121, 5);
    bool jA[12];
#pragma unroll
    for (int j = 0; j < 12; ++j) jA[j] = (min((c0ch + j) / 121, 5) == hA);

    float acc[12];
#pragma unroll
    for (int j = 0; j < 12; ++j) acc[j] = 0.f;

    for (int c0 = 0; c0 < deg; c0 += 64) {
        const int ce = min(64, deg - c0);
        int s;
        if (single) {                  // reuse pass-A registers
            s = ssave;
#pragma unroll
            for (int h = 0; h < 6; ++h)
                sal[w][h][lane] = __expf(w6s[h] - mx[h]) * sinv[h];
        } else {
            const bool val = (lane < ce);
            const int e = c0 + lane;
            s = val ? clampi(ss[r0 + e], 0, N_NODES - 1) : 0;
            const float* ep = es + (size_t)s * 6;
#pragma unroll
            for (int h = 0; h < 6; ++h) {
                float v = ep[h] + edn[h];
                v = (v > 0.f) ? v : 0.2f * v;
                sal[w][h][lane] = val ? __expf(v - mx[h]) * sinv[h] : 0.f;
            }
        }
        ssrc[w][lane] = s;
        const int ce4 = (ce + 3) & ~3;
        for (int eb = 0; eb < ce4; eb += 4) {
            int sg[4]; float aL[4], aH[4];
#pragma unroll
            for (int p = 0; p < 4; ++p) {
                sg[p] = ssrc[w][eb + p];
                aL[p] = sal[w][hA][eb + p];
                aH[p] = sal[w][hB][eb + p];
            }
#pragma unroll
            for (int p = 0; p < 4; ++p) {
                const bf16* gp = G + (size_t)sg[p] * SG + c0ch;
                bf16x4 g0 = *(const bf16x4*)gp;
                bf16x4 g1 = *(const bf16x4*)(gp + 4);
                bf16x4 g2 = *(const bf16x4*)(gp + 8);
#pragma unroll
                for (int j = 0; j < 4; ++j) acc[j]     += (jA[j]     ? aL[p] : aH[p]) * (float)g0[j];
#pragma unroll
                for (int j = 0; j < 4; ++j) acc[4 + j] += (jA[4 + j] ? aL[p] : aH[p]) * (float)g1[j];
#pragma unroll
                for (int j = 0; j < 4; ++j) acc[8 + j] += (jA[8 + j] ? aL[p] : aH[p]) * (float)g2[j];
            }
        }
    }

    // head-mean epilogue via wave-local LDS fold (wave-synchronous, in-order)
#pragma unroll
    for (int j = 0; j < 12; ++j) {
        int c = c0ch + j;
        if (c < 726) sfold[w][c] = acc[j];
    }
    const int outbf = flags[1];
    for (int c = lane; c < 121; c += 64) {
        float v = 0.f;
#pragma unroll
        for (int h = 0; h < 6; ++h) v += sfold[w][h * 121 + c];
        v *= (1.f / 6.f);
        v += (float)bgat[c] + (float)S[(size_t)n * SG + c] + (float)bskip[c];
        if (outbf) ((bf16*)out)[(size_t)n * sout + c] = (bf16)v;
        else       ((float*)out)[(size_t)n * sout + c] = v;
    }
}

// ----------------------------------------------------------------- launch ---
extern "C" void kernel_launch(void* const* d_in, const int* in_sizes, int n_in,
                              void* d_out, int out_size, void* d_ws, size_t ws_size,
                              hipStream_t stream)
{
    const void* x   = d_in[0];
    const int*  ei  = (const int*)d_in[1];
    const void* W1  = d_in[2];
    const void* Wl1 = d_in[6];
    const void* W2  = d_in[8];
    const void* Wl2 = d_in[12];
    const void* W3  = d_in[14];
    const void* Wl3 = d_in[18];

    P12 ps;
    ps.s[0] = d_in[3];  ps.s[1] = d_in[4];  ps.s[2] = d_in[5];  ps.s[3] = d_in[7];
    ps.s[4] = d_in[9];  ps.s[5] = d_in[10]; ps.s[6] = d_in[11]; ps.s[7] = d_in[13];
    ps.s[8] = d_in[15]; ps.s[9] = d_in[16]; ps.s[10] = d_in[17]; ps.s[11] = d_in[19];

    char* w = (char*)d_ws;
    auto alloc = [&](size_t bytes) {
        char* p = w;
        w += (bytes + 255) & ~(size_t)255;
        return p;
    };
    int*   flags = (int*)alloc(64);
    int*   cnt   = (int*)alloc((size_t)N_NODES * 4);
    int*   rp    = (int*)alloc((size_t)(N_NODES + 1) * 4);
    int*   cur   = (int*)alloc((size_t)N_NODES * 4);
    int*   ss    = (int*)alloc((size_t)E2 * 4);
    float* es    = (float*)alloc((size_t)N_NODES * 6 * 4);
    float* ed    = (float*)alloc((size_t)N_NODES * 6 * 4);
    bf16*  pool  = (bf16*)alloc((size_t)PO_END * 2);
    float* ws1   = (float*)alloc((size_t)64 * 4 * 4);
    float* wd1   = (float*)alloc((size_t)64 * 4 * 4);
    bf16*  bsum  = (bf16*)alloc((size_t)D1 * 2);
    bf16*  Bt    = (bf16*)alloc((size_t)D1 * KA * 2);        // layer-1 fused B^T
    bf16*  Bt2   = (bf16*)alloc((size_t)NP12 * 1024 * 2);    // layer-2 B^T
    bf16*  Bt3   = (bf16*)alloc((size_t)NP3 * 1024 * 2);     // layer-3 B^T
    bf16*  X     = (bf16*)alloc((size_t)N_NODES * D1 * 2);   // x1/x2
    bf16*  WS    = (bf16*)alloc((size_t)N_NODES * SG * 2);   // GEMM out [gat|skip]
    bf16*  A2    = WS;   // layer-1 A'' [N x KA] aliases WS (dead during layer 1)

    k_detect<<<1, 64, 0, stream>>>(ei, (const unsigned short*)x, flags);

    hipMemsetAsync(cnt, 0, N_NODES * 4, stream);
    k_count<<<(E2 + 255) / 256, 256, 0, stream>>>(ei, cnt, flags);
    k_scan<<<1, 256, 0, stream>>>(cnt, rp, cur);
    k_fill<<<(E2 + 255) / 256, 256, 0, stream>>>(ei, cur, ss, flags);

    const dim3 blk(256);
    const int MT = (N_NODES + 127) / 128;   // 157

    // ---- layer 1: veca -> merged prep (incl wcatT L2/L3) -> aggxw -> GEMM
    k_veca<<<64, 256, 0, stream>>>(W1, ps.s[0], ps.s[1], ps.s[2], ps.s[3],
                                   ws1, wd1, bsum, flags);
    k_prep<<<PB_PADX + PB_WF1 + PB_PAR + PB_LOG1 + PB_WC2 + PB_WC3, 256, 0, stream>>>(
        x, W1, Wl1, W2, Wl2, W3, Wl3, ps, A2, Bt, Bt2, Bt3, pool, ws1, wd1, es, ed, flags);
    k_aggxw<<<N_NODES / 4, 256, 0, stream>>>(A2, es, ed, rp, ss);
    k_gemm<true><<<MT * (D1 / 128), blk, 0, stream>>>(A2, Bt, X, N_NODES, KA, KA, KA, D1,
                                                      MT, D1 / 128, bsum);   // x1 = ELU(...)

    // ---- layer 2: GEMM -> logits -> aggregate
    k_gemm<false><<<MT * (NP12 / 128), blk, 0, stream>>>(X, Bt2, WS, N_NODES, 1024, 1024, 1024, SG,
                                                         MT, NP12 / 128, nullptr);
    k_logits<4, 256><<<N_NODES / 4, 256, 0, stream>>>(WS, pool + PO_A2S, pool + PO_A2D, es, ed);
    k_aggw<<<N_NODES / 4, 256, 0, stream>>>(
        WS, WS + D1, es, ed, rp, ss, pool + PO_B2, pool + PO_BL2, X, D1);

    // ---- layer 3: GEMM -> vectorized logits -> aggregate
    k_gemm<false><<<MT * (NP3 / 128), blk, 0, stream>>>(X, Bt3, WS, N_NODES, 1024, 1024, 1024, SG,
                                                        MT, NP3 / 128, nullptr);
    k_logits3w<<<N_NODES / 4, 256, 0, stream>>>(WS, pool + PO_A3S, pool + PO_A3D, es, ed);
    k_aggw3<<<N_NODES / 4, 256, 0, stream>>>(
        WS, WS + 726, es, ed, rp, ss, pool + PO_B3, pool + PO_BL3, d_out, 121, flags);
}